// Round 1
// baseline (1117.248 us; speedup 1.0000x reference)
//
#include <hip/hip_runtime.h>

// QP fixed-point solver, fully fused: one block = one batch element = one CU.
// n=64, m=128, alpha=beta=1, iters=1000, bs=256.
//
// Algebra: A = [[tD,tD],[I-2tD,I-2tD]] so with s = X1+X2:
//   x1' = tD s + mu ;  x2' = relu(s - 2 x1') ;  p = pinvH (x2' - b)
// => one 128x128 matvec + one 64x128 matvec per iteration.
// tD rows live in VGPRs (64/thread), pinvH in VGPRs (32/thread); only the
// 128-float s / (x2-b) vectors go through LDS (double-buffered, 1 barrier/iter).

#define NT 256
#define Nn 64
#define Mm 128
#define NITER 1000
#define NBATCH 256

// LDS float offsets (all float4-aligned where vector-read)
#define OFF_HP   0        // H padded [128][66]  (pad 66 kills transpose-read bank conflicts)
#define OFF_T    8448     // T = P^-1 H^T, later pinvH   [64][128]
#define OFF_PM   16640    // P -> P^-1, then G=H^T H -> G^-1   [64][66]
#define OFF_ROWK 20864    // 2x128 double-buffered pivot row (also gj64 row/col scratch)
#define OFF_DSH  21120    // pivot reciprocal broadcast
#define OFF_QV   21124    // q (64)
#define OFF_BV   21188    // b (128)
#define OFF_HQ   21316    // H P^-1 q - b (128)
#define OFF_PQ   21444    // P^-1 q (64)
#define OFF_SB   21508    // s double buffer 2x128
#define OFF_VB   21764    // (x2-b) double buffer 2x128
#define LDS_FLOATS 22020  // 88,080 bytes

// In-place Gauss-Jordan inversion of an SPD 64x64 (stride-66) matrix in LDS.
__device__ __forceinline__ void gj_invert64(float* __restrict__ A,
                                            float* __restrict__ rk,
                                            float* __restrict__ ck, int t)
{
    for (int k = 0; k < 64; ++k) {
        if (t < 64)       rk[t]    = A[k*66 + t];
        else if (t < 128) ck[t-64] = A[(t-64)*66 + k];
        __syncthreads();
        float d = 1.0f / rk[k];
        #pragma unroll
        for (int ii = 0; ii < 16; ++ii) {
            int o = ii*NT + t;
            int r = o >> 6, c = o & 63;
            float cr = ck[r];
            float rc = rk[c];
            float v;
            if (r == k)      v = (c == k) ? d : d * rc;
            else if (c == k) v = -d * cr;
            else             v = fmaf(-cr * d, rc, A[r*66 + c]);
            A[r*66 + c] = v;
        }
        __syncthreads();
    }
}

__global__ void __launch_bounds__(NT, 1)
qp_fused(const float* __restrict__ qg, const float* __restrict__ bg,
         const float* __restrict__ Pg, const float* __restrict__ Hg,
         float* __restrict__ out)
{
    __shared__ float lds[LDS_FLOATS];
    const int t    = threadIdx.x;
    const int beta = blockIdx.x;

    float* Hp   = lds + OFF_HP;
    float* Tm   = lds + OFF_T;
    float* Pm   = lds + OFF_PM;
    float* rowk = lds + OFF_ROWK;
    float* dsh  = lds + OFF_DSH;
    float* qv   = lds + OFF_QV;
    float* bv   = lds + OFF_BV;
    float* hq   = lds + OFF_HQ;
    float* pq   = lds + OFF_PQ;
    float* sb   = lds + OFF_SB;
    float* vb   = lds + OFF_VB;

    const float* Pgb = Pg + (size_t)beta * (Nn*Nn);
    const float* Hgb = Hg + (size_t)beta * (Mm*Nn);

    // ---- stage inputs -----------------------------------------------------
    for (int o = t; o < Mm*Nn; o += NT) Hp[(o>>6)*66 + (o&63)] = Hgb[o];
    for (int o = t; o < Nn*Nn; o += NT) Pm[(o>>6)*66 + (o&63)] = Pgb[o];
    if (t < Nn) qv[t] = qg[(size_t)beta*Nn + t];
    if (t < Mm) bv[t] = bg[(size_t)beta*Mm + t];
    __syncthreads();

    // ---- P^-1 -------------------------------------------------------------
    gj_invert64(Pm, rowk, rowk + 64, t);

    // pq = P^-1 q
    if (t < Nn) {
        float a = 0.f;
        for (int j = 0; j < Nn; ++j) a = fmaf(Pm[t*66 + j], qv[j], a);
        pq[t] = a;
    }
    __syncthreads();

    // hq = H pq - b
    if (t < Mm) {
        float a = 0.f;
        for (int n = 0; n < Nn; ++n) a = fmaf(Hp[t*66 + n], pq[n], a);
        hq[t] = a - bv[t];
    }
    // T[a][i] = sum_n Pinv[a][n] * H[i][n]
    for (int ii = 0; ii < 32; ++ii) {
        int o = ii*NT + t;
        int a = o >> 7, i = o & 127;
        float s = 0.f;
        for (int n = 0; n < Nn; ++n) s = fmaf(Pm[a*66 + n], Hp[i*66 + n], s);
        Tm[o] = s;
    }
    __syncthreads();

    // G = H^T H into Pm (Pinv dead)
    for (int ii = 0; ii < 16; ++ii) {
        int o = ii*NT + t;
        int a = o >> 6, b2 = o & 63;
        float s = 0.f;
        for (int i = 0; i < Mm; ++i) s = fmaf(Hp[i*66 + a], Hp[i*66 + b2], s);
        Pm[a*66 + b2] = s;
    }
    __syncthreads();
    gj_invert64(Pm, rowk, rowk + 64, t);    // Pm = (H^T H)^-1

    // ---- S = I + H T  directly into registers -----------------------------
    const int r  = t >> 1;      // tD row owned by this thread-pair
    const int h  = t & 1;       // column half
    const int c0 = h << 6;
    float td[64];
    #pragma unroll
    for (int j = 0; j < 64; ++j) td[j] = 0.f;
    for (int n = 0; n < Nn; ++n) {
        float hv = Hp[r*66 + n];
        const float4* t4 = reinterpret_cast<const float4*>(Tm + n*Mm + c0);
        #pragma unroll
        for (int jj = 0; jj < 16; ++jj) {
            float4 tv = t4[jj];
            td[4*jj+0] = fmaf(hv, tv.x, td[4*jj+0]);
            td[4*jj+1] = fmaf(hv, tv.y, td[4*jj+1]);
            td[4*jj+2] = fmaf(hv, tv.z, td[4*jj+2]);
            td[4*jj+3] = fmaf(hv, tv.w, td[4*jj+3]);
        }
    }
    #pragma unroll
    for (int j = 0; j < 64; ++j) td[j] += (c0 + j == r) ? 1.0f : 0.0f;
    __syncthreads();    // all reads of Tm done before overwrite

    // pinvH = G^-1 H^T into Tm (streaming, conflict-free)
    for (int ii = 0; ii < 32; ++ii) {
        int o = ii*NT + t;
        int a = o >> 7, i = o & 127;
        float s = 0.f;
        for (int b2 = 0; b2 < Nn; ++b2) s = fmaf(Pm[a*66 + b2], Hp[i*66 + b2], s);
        Tm[o] = s;
    }
    __syncthreads();

    // pinvH fragment -> regs: thread covers row ap, cols [32*qt, 32*qt+32)
    const int ap = t >> 2, qt = t & 3;
    float ph[32];
    {
        const float4* p4 = reinterpret_cast<const float4*>(Tm + ap*Mm + qt*32);
        #pragma unroll
        for (int jj = 0; jj < 8; ++jj) {
            float4 v = p4[jj];
            ph[4*jj+0] = v.x; ph[4*jj+1] = v.y; ph[4*jj+2] = v.z; ph[4*jj+3] = v.w;
        }
    }

    // ---- in-register Gauss-Jordan of SPD (I+S): td -> tD row fragment -----
    // Sweep-symmetry: A[r][k] = -A[k][r] if r already swept (r<k), else +A[k][r],
    // so only the pivot ROW is broadcast via LDS (double-buffered by k&1).
    // rka[k] += 1 trick: makes the generic FMA produce the correct column-k value.
    for (int k = 0; k < Mm; ++k) {
        float* rka = rowk + ((k & 1) << 7);
        if (r == k) {
            #pragma unroll
            for (int jj = 0; jj < 16; ++jj) {
                float4 v = make_float4(td[4*jj+0], td[4*jj+1], td[4*jj+2], td[4*jj+3]);
                reinterpret_cast<float4*>(rka + c0)[jj] = v;
            }
        }
        __syncthreads();
        if (t == 0) {
            float dd = 1.0f / rka[k];
            dsh[0] = dd;
            rka[k] += 1.0f;
        }
        __syncthreads();
        float d = dsh[0];
        if (r == k) {
            #pragma unroll
            for (int j = 0; j < 64; ++j) {
                float rv = rka[c0 + j];
                td[j] = (c0 + j == k) ? d : d * rv;
            }
        } else {
            float rkr = rka[r];
            float cd  = ((r < k) ? -rkr : rkr) * d;
            const float4* r4 = reinterpret_cast<const float4*>(rka + c0);
            #pragma unroll
            for (int jj = 0; jj < 16; ++jj) {
                float4 rv = r4[jj];
                td[4*jj+0] = fmaf(-cd, rv.x, td[4*jj+0]);
                td[4*jj+1] = fmaf(-cd, rv.y, td[4*jj+1]);
                td[4*jj+2] = fmaf(-cd, rv.z, td[4*jj+2]);
                td[4*jj+3] = fmaf(-cd, rv.w, td[4*jj+3]);
            }
        }
    }

    // ---- mu fragment: mur = (tD hq)[r] ------------------------------------
    float mur;
    {
        const float4* h4 = reinterpret_cast<const float4*>(hq + c0);
        float a0=0,a1=0,a2=0,a3=0;
        #pragma unroll
        for (int jj = 0; jj < 16; ++jj) {
            float4 hv = h4[jj];
            a0 = fmaf(td[4*jj+0], hv.x, a0);
            a1 = fmaf(td[4*jj+1], hv.y, a1);
            a2 = fmaf(td[4*jj+2], hv.z, a2);
            a3 = fmaf(td[4*jj+3], hv.w, a3);
        }
        float yp = (a0+a1)+(a2+a3);
        mur = yp + __shfl_xor(yp, 1);
    }
    const float brr = bv[r];

    float* outX = out + (size_t)beta * ((NITER+1) * 2*Mm);
    float* outP = out + (size_t)NBATCH * ((NITER+1) * 2*Mm) + (size_t)beta * ((NITER+1) * Nn);

    // ---- k = 0: X0 = 0, p0 = -pinvH b -------------------------------------
    if (h == 0) sb[r] = 0.f;
    else        vb[r] = -brr;
    outX[t] = 0.f;
    __syncthreads();
    {
        const float4* v4 = reinterpret_cast<const float4*>(vb + qt*32);
        float a0=0,a1=0,a2=0,a3=0;
        #pragma unroll
        for (int jj = 0; jj < 8; ++jj) {
            float4 vv = v4[jj];
            a0 = fmaf(ph[4*jj+0], vv.x, a0);
            a1 = fmaf(ph[4*jj+1], vv.y, a1);
            a2 = fmaf(ph[4*jj+2], vv.z, a2);
            a3 = fmaf(ph[4*jj+3], vv.w, a3);
        }
        float pp = (a0+a1)+(a2+a3);
        pp += __shfl_xor(pp, 1);
        pp += __shfl_xor(pp, 2);
        if (qt == 0) outP[ap] = pp;
    }

    // ---- main sequential loop: 1 barrier per iteration --------------------
    float sr = 0.f;     // this pair's s[r], kept in-register
    for (int k = 1; k <= NITER; ++k) {
        const int src = (k - 1) & 1, dst = k & 1;
        const float4* s4 = reinterpret_cast<const float4*>(sb + src*Mm + c0);
        float a0=0,a1=0,a2=0,a3=0;
        #pragma unroll
        for (int jj = 0; jj < 16; ++jj) {
            float4 sv = s4[jj];
            a0 = fmaf(td[4*jj+0], sv.x, a0);
            a1 = fmaf(td[4*jj+1], sv.y, a1);
            a2 = fmaf(td[4*jj+2], sv.z, a2);
            a3 = fmaf(td[4*jj+3], sv.w, a3);
        }
        float yp = (a0+a1)+(a2+a3);
        float y  = yp + __shfl_xor(yp, 1);          // pair-reduce: full row dot
        float x1 = y + mur;
        float x2 = fmaxf(fmaf(-2.0f, x1, sr), 0.0f);
        sr = x1 + x2;
        if (h == 0) { sb[dst*Mm + r] = sr;       outX[(size_t)k*256 + r]       = x1; }
        else        { vb[dst*Mm + r] = x2 - brr; outX[(size_t)k*256 + 128 + r] = x2; }
        __syncthreads();
        // p_k = pinvH (x2 - b)
        const float4* v4 = reinterpret_cast<const float4*>(vb + dst*Mm + qt*32);
        float p0a=0,p1a=0,p2a=0,p3a=0;
        #pragma unroll
        for (int jj = 0; jj < 8; ++jj) {
            float4 vv = v4[jj];
            p0a = fmaf(ph[4*jj+0], vv.x, p0a);
            p1a = fmaf(ph[4*jj+1], vv.y, p1a);
            p2a = fmaf(ph[4*jj+2], vv.z, p2a);
            p3a = fmaf(ph[4*jj+3], vv.w, p3a);
        }
        float pp = (p0a+p1a)+(p2a+p3a);
        pp += __shfl_xor(pp, 1);
        pp += __shfl_xor(pp, 2);
        if (qt == 0) outP[(size_t)k*Nn + ap] = pp;
    }
}

extern "C" void kernel_launch(void* const* d_in, const int* in_sizes, int n_in,
                              void* d_out, int out_size, void* d_ws, size_t ws_size,
                              hipStream_t stream)
{
    const float* q = (const float*)d_in[0];
    const float* b = (const float*)d_in[1];
    const float* P = (const float*)d_in[2];
    const float* H = (const float*)d_in[3];
    float* out = (float*)d_out;
    // iters (d_in[4]) is fixed at 1000 per the reference; hardcoded as NITER.
    hipLaunchKernelGGL(qp_fused, dim3(NBATCH), dim3(NT), 0, stream,
                       q, b, P, H, out);
}

// Round 2
// 1037.938 us; speedup vs baseline: 1.0764x; 1.0764x over previous
//
#include <hip/hip_runtime.h>

// QP fixed-point solver, 3-kernel split. n=64, m=128, alpha=beta=1, iters=1000, bs=256.
//
// Algebra: A = [[tD,tD],[I-2tD,I-2tD]] so with s = X1+X2:
//   x1' = tD s + mu ;  x2' = relu(s - 2 x1') ;  p = pinvH (x2' - b)
// K1: per-batch setup (P^-1, tD = (I+H P^-1 H^T)^-1 via in-register GJ, pinvH, mu) -> scratch
// K2: serial 1000-iter loop, ONLY the 128x128 matvec. 2 rows/thread x 32-col quarter,
//     padded s layout (stride-36 groups, conflict-free), DPP quad reduce, 1 barrier/iter.
// K3: p_k = pinvH x2_k - pinvH b for all k in parallel (x2 read back from d_out).

#define NT 256
#define Nn 64
#define Mm 128
#define NITER 1000
#define NBATCH 256

// scratch layout per batch (floats)
#define SCR_TD 0
#define SCR_MU 16384
#define SCR_PH 16512
#define SCR_FLOATS 24704

// ---- K1 LDS offsets (floats) ----
#define OFF_HP   0        // H padded [128][66]
#define OFF_T    8448     // T = P^-1 H^T, later pinvH   [64][128]
#define OFF_PM   16640    // P -> P^-1, then G=H^T H -> G^-1   [64][66]
#define OFF_ROWK 20864    // 2x128 pivot-row double buffer (also gj64 row/col scratch)
#define OFF_DSH  21120
#define OFF_QV   21124
#define OFF_BV   21188
#define OFF_HQ   21316
#define OFF_PQ   21444
#define LDS_FLOATS 21508

// In-place Gauss-Jordan inversion of an SPD 64x64 (stride-66) matrix in LDS.
__device__ __forceinline__ void gj_invert64(float* __restrict__ A,
                                            float* __restrict__ rk,
                                            float* __restrict__ ck, int t)
{
    for (int k = 0; k < 64; ++k) {
        if (t < 64)       rk[t]    = A[k*66 + t];
        else if (t < 128) ck[t-64] = A[(t-64)*66 + k];
        __syncthreads();
        float d = 1.0f / rk[k];
        #pragma unroll
        for (int ii = 0; ii < 16; ++ii) {
            int o = ii*NT + t;
            int r = o >> 6, c = o & 63;
            float cr = ck[r];
            float rc = rk[c];
            float v;
            if (r == k)      v = (c == k) ? d : d * rc;
            else if (c == k) v = -d * cr;
            else             v = fmaf(-cr * d, rc, A[r*66 + c]);
            A[r*66 + c] = v;
        }
        __syncthreads();
    }
}

// quad (4-lane) sum via DPP quad_perm: xor1 = [1,0,3,2] = 0xB1, xor2 = [2,3,0,1] = 0x4E
__device__ __forceinline__ float qsum(float x)
{
    int p;
    p = __builtin_amdgcn_update_dpp(0, __float_as_int(x), 0xB1, 0xF, 0xF, true);
    x += __int_as_float(p);
    p = __builtin_amdgcn_update_dpp(0, __float_as_int(x), 0x4E, 0xF, 0xF, true);
    x += __int_as_float(p);
    return x;
}

// =============================== K1: setup ===============================
__global__ void __launch_bounds__(NT, 1)
qp_setup(const float* __restrict__ qg, const float* __restrict__ bg,
         const float* __restrict__ Pg, const float* __restrict__ Hg,
         float* __restrict__ scr, long scrStride)
{
    __shared__ float lds[LDS_FLOATS];
    const int t    = threadIdx.x;
    const int beta = blockIdx.x;

    float* Hp   = lds + OFF_HP;
    float* Tm   = lds + OFF_T;
    float* Pm   = lds + OFF_PM;
    float* rowk = lds + OFF_ROWK;
    float* dsh  = lds + OFF_DSH;
    float* qv   = lds + OFF_QV;
    float* bv   = lds + OFF_BV;
    float* hq   = lds + OFF_HQ;
    float* pq   = lds + OFF_PQ;

    const float* Pgb = Pg + (size_t)beta * (Nn*Nn);
    const float* Hgb = Hg + (size_t)beta * (Mm*Nn);
    float* scb = scr + (size_t)beta * scrStride;

    // ---- stage inputs ----
    for (int o = t; o < Mm*Nn; o += NT) Hp[(o>>6)*66 + (o&63)] = Hgb[o];
    for (int o = t; o < Nn*Nn; o += NT) Pm[(o>>6)*66 + (o&63)] = Pgb[o];
    if (t < Nn) qv[t] = qg[(size_t)beta*Nn + t];
    if (t < Mm) bv[t] = bg[(size_t)beta*Mm + t];
    __syncthreads();

    // ---- P^-1 ----
    gj_invert64(Pm, rowk, rowk + 64, t);

    if (t < Nn) {
        float a = 0.f;
        for (int j = 0; j < Nn; ++j) a = fmaf(Pm[t*66 + j], qv[j], a);
        pq[t] = a;
    }
    __syncthreads();

    if (t < Mm) {
        float a = 0.f;
        for (int n = 0; n < Nn; ++n) a = fmaf(Hp[t*66 + n], pq[n], a);
        hq[t] = a - bv[t];
    }
    // T[a][i] = sum_n Pinv[a][n] * H[i][n]
    for (int ii = 0; ii < 32; ++ii) {
        int o = ii*NT + t;
        int a = o >> 7, i = o & 127;
        float s = 0.f;
        for (int n = 0; n < Nn; ++n) s = fmaf(Pm[a*66 + n], Hp[i*66 + n], s);
        Tm[o] = s;
    }
    __syncthreads();

    // G = H^T H into Pm
    for (int ii = 0; ii < 16; ++ii) {
        int o = ii*NT + t;
        int a = o >> 6, b2 = o & 63;
        float s = 0.f;
        for (int i = 0; i < Mm; ++i) s = fmaf(Hp[i*66 + a], Hp[i*66 + b2], s);
        Pm[a*66 + b2] = s;
    }
    __syncthreads();
    gj_invert64(Pm, rowk, rowk + 64, t);    // Pm = (H^T H)^-1

    // ---- S = I + H T into registers (pair layout: row r = t>>1, cols 64h..) ----
    const int r  = t >> 1;
    const int h  = t & 1;
    const int c0 = h << 6;
    float td[64];
    #pragma unroll
    for (int j = 0; j < 64; ++j) td[j] = 0.f;
    for (int n = 0; n < Nn; ++n) {
        float hv = Hp[r*66 + n];
        const float4* t4 = reinterpret_cast<const float4*>(Tm + n*Mm + c0);
        #pragma unroll
        for (int jj = 0; jj < 16; ++jj) {
            float4 tv = t4[jj];
            td[4*jj+0] = fmaf(hv, tv.x, td[4*jj+0]);
            td[4*jj+1] = fmaf(hv, tv.y, td[4*jj+1]);
            td[4*jj+2] = fmaf(hv, tv.z, td[4*jj+2]);
            td[4*jj+3] = fmaf(hv, tv.w, td[4*jj+3]);
        }
    }
    #pragma unroll
    for (int j = 0; j < 64; ++j) td[j] += (c0 + j == r) ? 1.0f : 0.0f;
    __syncthreads();

    // pinvH = G^-1 H^T into Tm
    for (int ii = 0; ii < 32; ++ii) {
        int o = ii*NT + t;
        int a = o >> 7, i = o & 127;
        float s = 0.f;
        for (int b2 = 0; b2 < Nn; ++b2) s = fmaf(Pm[a*66 + b2], Hp[i*66 + b2], s);
        Tm[o] = s;
    }
    __syncthreads();

    // ---- in-register Gauss-Jordan of SPD (I+S): td -> tD row fragment ----
    for (int k = 0; k < Mm; ++k) {
        float* rka = rowk + ((k & 1) << 7);
        if (r == k) {
            #pragma unroll
            for (int jj = 0; jj < 16; ++jj) {
                float4 v = make_float4(td[4*jj+0], td[4*jj+1], td[4*jj+2], td[4*jj+3]);
                reinterpret_cast<float4*>(rka + c0)[jj] = v;
            }
        }
        __syncthreads();
        if (t == 0) {
            float dd = 1.0f / rka[k];
            dsh[0] = dd;
            rka[k] += 1.0f;
        }
        __syncthreads();
        float d = dsh[0];
        if (r == k) {
            #pragma unroll
            for (int j = 0; j < 64; ++j) {
                float rv = rka[c0 + j];
                td[j] = (c0 + j == k) ? d : d * rv;
            }
        } else {
            float rkr = rka[r];
            float cd  = ((r < k) ? -rkr : rkr) * d;
            const float4* r4 = reinterpret_cast<const float4*>(rka + c0);
            #pragma unroll
            for (int jj = 0; jj < 16; ++jj) {
                float4 rv = r4[jj];
                td[4*jj+0] = fmaf(-cd, rv.x, td[4*jj+0]);
                td[4*jj+1] = fmaf(-cd, rv.y, td[4*jj+1]);
                td[4*jj+2] = fmaf(-cd, rv.z, td[4*jj+2]);
                td[4*jj+3] = fmaf(-cd, rv.w, td[4*jj+3]);
            }
        }
    }

    // ---- mu fragment: mur = (tD hq)[r] ----
    float mur;
    {
        const float4* h4 = reinterpret_cast<const float4*>(hq + c0);
        float a0=0,a1=0,a2=0,a3=0;
        #pragma unroll
        for (int jj = 0; jj < 16; ++jj) {
            float4 hv = h4[jj];
            a0 = fmaf(td[4*jj+0], hv.x, a0);
            a1 = fmaf(td[4*jj+1], hv.y, a1);
            a2 = fmaf(td[4*jj+2], hv.z, a2);
            a3 = fmaf(td[4*jj+3], hv.w, a3);
        }
        float yp = (a0+a1)+(a2+a3);
        mur = yp + __shfl_xor(yp, 1);
    }

    // ---- write scratch: tD row-major, mu, pinvH ----
    {
        float4* dst4 = reinterpret_cast<float4*>(scb + SCR_TD + r*Mm + c0);
        #pragma unroll
        for (int jj = 0; jj < 16; ++jj)
            dst4[jj] = make_float4(td[4*jj+0], td[4*jj+1], td[4*jj+2], td[4*jj+3]);
    }
    if (h == 0) scb[SCR_MU + r] = mur;
    {
        const float4* src4 = reinterpret_cast<const float4*>(Tm);
        float4* dst4 = reinterpret_cast<float4*>(scb + SCR_PH);
        for (int o = t; o < (Nn*Mm)/4; o += NT) dst4[o] = src4[o];
    }
}

// =============================== K2: serial loop ===============================
// thread t: qt = t&3 (col quarter [32qt,32qt+32)), r = t>>2; owns rows r and r+64.
// s stored padded: s[j] at index (j>>5)*36 + (j&31)  -> 4 read groups in disjoint banks.
__global__ void __launch_bounds__(NT, 1)
qp_loop(const float* __restrict__ scr, long scrStride, float* __restrict__ out)
{
    __shared__ float sb[2][144];
    const int t    = threadIdx.x;
    const int beta = blockIdx.x;
    const int qt = t & 3, r = t >> 2;
    const float* sc = scr + (size_t)beta * scrStride;

    // tD fragments -> registers
    float td0[32], td1[32];
    {
        const float4* g0 = reinterpret_cast<const float4*>(sc + SCR_TD + r*Mm + 32*qt);
        const float4* g1 = reinterpret_cast<const float4*>(sc + SCR_TD + (r+64)*Mm + 32*qt);
        #pragma unroll
        for (int jj = 0; jj < 8; ++jj) {
            float4 v = g0[jj];
            td0[4*jj+0]=v.x; td0[4*jj+1]=v.y; td0[4*jj+2]=v.z; td0[4*jj+3]=v.w;
            float4 w = g1[jj];
            td1[4*jj+0]=w.x; td1[4*jj+1]=w.y; td1[4*jj+2]=w.z; td1[4*jj+3]=w.w;
        }
    }
    const float mu0 = sc[SCR_MU + r];
    const float mu1 = sc[SCR_MU + 64 + r];

    float* outX = out + (size_t)beta * ((size_t)(NITER+1) * 2*Mm);
    outX[t] = 0.f;                      // X0 = 0
    if (t < 144) sb[0][t] = 0.f;        // s0 = 0
    float sr0 = 0.f, sr1 = 0.f;
    const int woff0 = r       + ((r >> 5) << 2);        // layout index of s[r]
    const int woff1 = r + 72  + ((r >> 5) << 2);        // layout index of s[r+64]
    const int waddr = (qt == 0) ? woff0 : woff1;
    __syncthreads();

    int cur = 0;
    for (int k = 1; k <= NITER; ++k) {
        const float4* s4 = reinterpret_cast<const float4*>(&sb[cur][36*qt]);
        float4 v[8];
        #pragma unroll
        for (int jj = 0; jj < 8; ++jj) v[jj] = s4[jj];
        float a00=0,a01=0,a02=0,a03=0, a10=0,a11=0,a12=0,a13=0;
        #pragma unroll
        for (int jj = 0; jj < 8; ++jj) {
            a00 = fmaf(td0[4*jj+0], v[jj].x, a00);
            a01 = fmaf(td0[4*jj+1], v[jj].y, a01);
            a02 = fmaf(td0[4*jj+2], v[jj].z, a02);
            a03 = fmaf(td0[4*jj+3], v[jj].w, a03);
            a10 = fmaf(td1[4*jj+0], v[jj].x, a10);
            a11 = fmaf(td1[4*jj+1], v[jj].y, a11);
            a12 = fmaf(td1[4*jj+2], v[jj].z, a12);
            a13 = fmaf(td1[4*jj+3], v[jj].w, a13);
        }
        float y0 = qsum((a00+a01)+(a02+a03));   // quad-uniform full row dots
        float y1 = qsum((a10+a11)+(a12+a13));

        // all 4 quad lanes track both rows' state (redundant, keeps lanes uniform)
        float x1_0 = y0 + mu0;
        float x2_0 = fmaxf(fmaf(-2.0f, x1_0, sr0), 0.0f);
        sr0 = x1_0 + x2_0;
        float x1_1 = y1 + mu1;
        float x2_1 = fmaxf(fmaf(-2.0f, x1_1, sr1), 0.0f);
        sr1 = x1_1 + x2_1;

        if (qt < 2) sb[cur ^ 1][waddr] = (qt == 0) ? sr0 : sr1;

        float val = (qt == 0) ? x1_0 : (qt == 1) ? x2_0 : (qt == 2) ? x1_1 : x2_1;
        outX[(size_t)k*256 + ((qt & 1) << 7) + ((qt & 2) << 5) + r] = val;

        cur ^= 1;
        __syncthreads();
    }
}

// =============================== K3: p outputs ===============================
// thread t: a = t&63 (p row), ks = t>>6 (iteration slot, stride 4).
__global__ void __launch_bounds__(NT, 1)
qp_pout(const float* scr, long scrStride, const float* bg, float* out)
{
    const int t    = threadIdx.x;
    const int beta = blockIdx.x;
    const int a = t & 63, ks = t >> 6;
    const float* sc = scr + (size_t)beta * scrStride;

    float phr[128];
    {
        const float4* pg = reinterpret_cast<const float4*>(sc + SCR_PH + a*Mm);
        #pragma unroll
        for (int jj = 0; jj < 32; ++jj) {
            float4 v = pg[jj];
            phr[4*jj+0]=v.x; phr[4*jj+1]=v.y; phr[4*jj+2]=v.z; phr[4*jj+3]=v.w;
        }
    }
    float c0 = 0.f;
    {
        const float4* b4 = reinterpret_cast<const float4*>(bg + (size_t)beta*Mm);
        #pragma unroll
        for (int jj = 0; jj < 32; ++jj) {
            float4 v = b4[jj];
            c0 = fmaf(phr[4*jj+0], v.x, c0);
            c0 = fmaf(phr[4*jj+1], v.y, c0);
            c0 = fmaf(phr[4*jj+2], v.z, c0);
            c0 = fmaf(phr[4*jj+3], v.w, c0);
        }
    }
    __syncthreads();   // all scratch reads done before any outP writes (fallback placement)

    const float* Xb   = out + (size_t)beta * ((size_t)(NITER+1) * 2*Mm);
    float*       outP = out + (size_t)NBATCH * ((size_t)(NITER+1) * 2*Mm)
                            + (size_t)beta * ((size_t)(NITER+1) * Nn);

    for (int k = ks; k <= NITER; k += 4) {
        const float4* x4 = reinterpret_cast<const float4*>(Xb + (size_t)k*256 + 128);
        float acc = -c0;
        #pragma unroll
        for (int jj = 0; jj < 32; ++jj) {
            float4 v = x4[jj];
            acc = fmaf(phr[4*jj+0], v.x, acc);
            acc = fmaf(phr[4*jj+1], v.y, acc);
            acc = fmaf(phr[4*jj+2], v.z, acc);
            acc = fmaf(phr[4*jj+3], v.w, acc);
        }
        outP[(size_t)k*Nn + a] = acc;
    }
}

extern "C" void kernel_launch(void* const* d_in, const int* in_sizes, int n_in,
                              void* d_out, int out_size, void* d_ws, size_t ws_size,
                              hipStream_t stream)
{
    const float* q = (const float*)d_in[0];
    const float* b = (const float*)d_in[1];
    const float* P = (const float*)d_in[2];
    const float* H = (const float*)d_in[3];
    float* out = (float*)d_out;

    // scratch: prefer d_ws; else carve from the outP region (K2 never writes outP,
    // K3 reads its scratch rows before writing and fully overwrites the region).
    size_t need = (size_t)NBATCH * SCR_FLOATS * sizeof(float);
    float* scr;
    long stride;
    if (ws_size >= need) { scr = (float*)d_ws; stride = SCR_FLOATS; }
    else {
        scr = out + (size_t)NBATCH * ((size_t)(NITER+1) * 2*Mm);
        stride = (long)(NITER+1) * Nn;   // 64064 >= 24704
    }

    hipLaunchKernelGGL(qp_setup, dim3(NBATCH), dim3(NT), 0, stream, q, b, P, H, scr, stride);
    hipLaunchKernelGGL(qp_loop,  dim3(NBATCH), dim3(NT), 0, stream, scr, stride, out);
    hipLaunchKernelGGL(qp_pout,  dim3(NBATCH), dim3(NT), 0, stream, scr, stride, b, out);
}

// Round 3
// 662.816 us; speedup vs baseline: 1.6856x; 1.5660x over previous
//
#include <hip/hip_runtime.h>

// QP fixed-point solver, 2-kernel. n=64, m=128, alpha=beta=1, iters=1000, bs=256.
//
// Algebra: A = [[tD,tD],[I-2tD,I-2tD]] so with s = X1+X2:
//   x1' = tD s + mu ;  x2' = relu(s - 2 x1') ;  p = pinvH (x2' - b)
// K1 (512 thr): setup. G=H^T H (register-tiled), dual-interleaved GJ inversion of
//   {P, G}, W = H*Pinv & pinvH = Ginv*H^T via hoisted H-rows, S = W*H^T into
//   32-wide register fragments, in-register GJ-128 of (I+S) -> tD, mu. To scratch.
// K2 (512 thr, wave-specialized): waves 0-3 = serial matvec (x1,x2,s); waves 4-7 =
//   p_{k-1} = pinvH * vb[prev] pipelined one iteration behind. 1 barrier/iter.

#define NT1 512
#define NT2 512
#define Nn 64
#define Mm 128
#define NITER 1000
#define NBATCH 256

// scratch per batch (floats)
#define SCR_TD 0
#define SCR_MU 16384
#define SCR_PH 16512
#define SCR_FLOATS 24704

// K1 LDS offsets (floats)
#define OFF_HP   0        // H  [128][66]
#define OFF_WM   8448     // W = H*Pinv  [128][66]
#define OFF_PM   16896    // P -> Pinv   [64][66]
#define OFF_GM   21120    // G=H^T H -> Ginv [64][66]
#define OFF_ROWK 25344    // 256: dual-gj staging / GJ-128 pivot-row dbuf
#define OFF_DSH  25600
#define OFF_QV   25604
#define OFF_BV   25668
#define OFF_HQ   25796
#define OFF_PQ   25924
#define LDS1_FLOATS 25988   // 103,952 B

// quad (4-lane) sum via DPP quad_perm: [1,0,3,2]=0xB1, [2,3,0,1]=0x4E
__device__ __forceinline__ float qsum(float x)
{
    int p;
    p = __builtin_amdgcn_update_dpp(0, __float_as_int(x), 0xB1, 0xF, 0xF, true);
    x += __int_as_float(p);
    p = __builtin_amdgcn_update_dpp(0, __float_as_int(x), 0x4E, 0xF, 0xF, true);
    x += __int_as_float(p);
    return x;
}

// =============================== K1: setup ===============================
__global__ void __launch_bounds__(NT1, 2)
qp_setup(const float* __restrict__ qg, const float* __restrict__ bg,
         const float* __restrict__ Pg, const float* __restrict__ Hg,
         float* __restrict__ scr, long scrStride)
{
    __shared__ float lds[LDS1_FLOATS];
    const int t    = threadIdx.x;
    const int beta = blockIdx.x;

    float* Hp   = lds + OFF_HP;
    float* Wm   = lds + OFF_WM;
    float* Pm   = lds + OFF_PM;
    float* Gm   = lds + OFF_GM;
    float* rowk = lds + OFF_ROWK;
    float* dsh  = lds + OFF_DSH;
    float* qv   = lds + OFF_QV;
    float* bv   = lds + OFF_BV;
    float* hq   = lds + OFF_HQ;
    float* pq   = lds + OFF_PQ;

    const float* Hgb = Hg + (size_t)beta * (Mm*Nn);
    const float* Pgb = Pg + (size_t)beta * (Nn*Nn);
    float* scb = scr + (size_t)beta * scrStride;

    // ---- stage inputs (float4 global reads, float2 LDS writes: stride 66) ----
    {
        const float4* Hg4 = reinterpret_cast<const float4*>(Hgb);
        for (int o4 = t; o4 < (Mm*Nn)/4; o4 += NT1) {
            float4 v = Hg4[o4];
            int i = o4 >> 4, n = (o4 & 15) << 2;
            float* d = Hp + i*66 + n;
            *reinterpret_cast<float2*>(d)     = make_float2(v.x, v.y);
            *reinterpret_cast<float2*>(d + 2) = make_float2(v.z, v.w);
        }
        const float4* Pg4 = reinterpret_cast<const float4*>(Pgb);
        for (int o4 = t; o4 < (Nn*Nn)/4; o4 += NT1) {
            float4 v = Pg4[o4];
            int i = o4 >> 4, n = (o4 & 15) << 2;
            float* d = Pm + i*66 + n;
            *reinterpret_cast<float2*>(d)     = make_float2(v.x, v.y);
            *reinterpret_cast<float2*>(d + 2) = make_float2(v.z, v.w);
        }
        if (t < Nn) qv[t] = qg[(size_t)beta*Nn + t];
        else if (t < Nn + Mm) bv[t - Nn] = bg[(size_t)beta*Mm + (t - Nn)];
    }
    __syncthreads();

    // ---- G = H^T H, register-tiled 4x2 ----
    {
        const int ra0 = (t >> 5) << 2;   // 4 rows
        const int cb0 = (t & 31) << 1;   // 2 cols
        float g00=0,g01=0,g10=0,g11=0,g20=0,g21=0,g30=0,g31=0;
        for (int i = 0; i < Mm; ++i) {
            const float* hr = Hp + i*66;
            float2 a01 = *reinterpret_cast<const float2*>(hr + ra0);
            float2 a23 = *reinterpret_cast<const float2*>(hr + ra0 + 2);
            float2 bb  = *reinterpret_cast<const float2*>(hr + cb0);
            g00 = fmaf(a01.x, bb.x, g00); g01 = fmaf(a01.x, bb.y, g01);
            g10 = fmaf(a01.y, bb.x, g10); g11 = fmaf(a01.y, bb.y, g11);
            g20 = fmaf(a23.x, bb.x, g20); g21 = fmaf(a23.x, bb.y, g21);
            g30 = fmaf(a23.y, bb.x, g30); g31 = fmaf(a23.y, bb.y, g31);
        }
        *reinterpret_cast<float2*>(Gm + (ra0+0)*66 + cb0) = make_float2(g00, g01);
        *reinterpret_cast<float2*>(Gm + (ra0+1)*66 + cb0) = make_float2(g10, g11);
        *reinterpret_cast<float2*>(Gm + (ra0+2)*66 + cb0) = make_float2(g20, g21);
        *reinterpret_cast<float2*>(Gm + (ra0+3)*66 + cb0) = make_float2(g30, g31);
    }
    __syncthreads();

    // ---- dual-interleaved Gauss-Jordan: Pm -> P^-1 and Gm -> G^-1 ----
    {
        float* rkP = rowk;
        float* ckP = rowk + 64;
        float* rkG = rowk + 128;
        float* ckG = rowk + 192;
        for (int k = 0; k < 64; ++k) {
            if (t < 64)        rkP[t]       = Pm[k*66 + t];
            else if (t < 128)  ckP[t - 64]  = Pm[(t-64)*66 + k];
            else if (t < 192)  rkG[t - 128] = Gm[k*66 + (t-128)];
            else if (t < 256)  ckG[t - 192] = Gm[(t-192)*66 + k];
            __syncthreads();
            float dP = 1.0f / rkP[k];
            float dG = 1.0f / rkG[k];
            #pragma unroll
            for (int ii = 0; ii < 16; ++ii) {
                int o = ii*NT1 + t;
                int rr = (o >> 6) & 63, cc = o & 63;
                float* A  = (ii < 8) ? Pm  : Gm;
                float* rk = (ii < 8) ? rkP : rkG;
                float* ck = (ii < 8) ? ckP : ckG;
                float d   = (ii < 8) ? dP  : dG;
                float cr = ck[rr];
                float rc = rk[cc];
                float v;
                if (rr == k)      v = (cc == k) ? d : d * rc;
                else if (cc == k) v = -d * cr;
                else              v = fmaf(-cr * d, rc, A[rr*66 + cc]);
                A[rr*66 + cc] = v;
            }
            __syncthreads();
        }
    }

    // ---- pq = Pinv q ----
    if (t < Nn) {
        const float2* pr = reinterpret_cast<const float2*>(Pm + t*66);
        const float2* q2 = reinterpret_cast<const float2*>(qv);
        float s0 = 0.f, s1 = 0.f;
        #pragma unroll
        for (int j = 0; j < 32; ++j) {
            float2 a = pr[j], b2 = q2[j];
            s0 = fmaf(a.x, b2.x, s0);
            s1 = fmaf(a.y, b2.y, s1);
        }
        pq[t] = s0 + s1;
    }
    __syncthreads();

    // ---- hoist H row (iw = t&127); W, pinvH, hq ----
    const int iw = t & 127;
    const int a0 = (t >> 7) << 4;   // 16 a's per thread
    float hrow[64];
    {
        const float2* hr2 = reinterpret_cast<const float2*>(Hp + iw*66);
        #pragma unroll
        for (int j = 0; j < 32; ++j) { float2 v = hr2[j]; hrow[2*j] = v.x; hrow[2*j+1] = v.y; }
    }
    for (int aa = 0; aa < 16; ++aa) {       // W[iw][a] = H row iw . Pinv row a
        int a = a0 + aa;
        const float2* pr = reinterpret_cast<const float2*>(Pm + a*66);
        float s0 = 0.f, s1 = 0.f;
        #pragma unroll
        for (int j = 0; j < 32; ++j) {
            float2 v = pr[j];
            s0 = fmaf(hrow[2*j],   v.x, s0);
            s1 = fmaf(hrow[2*j+1], v.y, s1);
        }
        Wm[iw*66 + a] = s0 + s1;
    }
    for (int aa = 0; aa < 16; ++aa) {       // pinvH[a][iw] = Ginv row a . H row iw
        int a = a0 + aa;
        const float2* gr = reinterpret_cast<const float2*>(Gm + a*66);
        float s0 = 0.f, s1 = 0.f;
        #pragma unroll
        for (int j = 0; j < 32; ++j) {
            float2 v = gr[j];
            s0 = fmaf(hrow[2*j],   v.x, s0);
            s1 = fmaf(hrow[2*j+1], v.y, s1);
        }
        scb[SCR_PH + a*Mm + iw] = s0 + s1;
    }
    if (t < Mm) {                           // hq[t] = H row t . pq - b  (hrow == row t)
        const float2* q2 = reinterpret_cast<const float2*>(pq);
        float s0 = 0.f, s1 = 0.f;
        #pragma unroll
        for (int j = 0; j < 32; ++j) {
            float2 v = q2[j];
            s0 = fmaf(hrow[2*j],   v.x, s0);
            s1 = fmaf(hrow[2*j+1], v.y, s1);
        }
        hq[t] = s0 + s1 - bv[t];
    }
    __syncthreads();

    // ---- S = I + W H^T into 32-wide register fragments ----
    const int r   = t >> 2;
    const int q2t = t & 3;
    const int c0  = q2t << 5;
    float td[32];
    {
        float wrow[64];
        const float2* wr2 = reinterpret_cast<const float2*>(Wm + r*66);
        #pragma unroll
        for (int j = 0; j < 32; ++j) { float2 v = wr2[j]; wrow[2*j] = v.x; wrow[2*j+1] = v.y; }
        for (int cc = 0; cc < 32; ++cc) {
            int c = c0 + cc;
            const float2* hc = reinterpret_cast<const float2*>(Hp + c*66);
            float s0 = 0.f, s1 = 0.f;
            #pragma unroll
            for (int j = 0; j < 32; ++j) {
                float2 v = hc[j];
                s0 = fmaf(wrow[2*j],   v.x, s0);
                s1 = fmaf(wrow[2*j+1], v.y, s1);
            }
            td[cc] = s0 + s1 + ((c == r) ? 1.0f : 0.0f);
        }
    }
    __syncthreads();

    // ---- in-register Gauss-Jordan of SPD (I+S): td -> tD fragment ----
    // Sweep-symmetry: A[r][k] = -A[k][r] if r<k (already swept), else +A[k][r].
    // rka[k] += 1 trick makes the generic FMA produce the correct column-k value.
    for (int k = 0; k < Mm; ++k) {
        float* rka = rowk + ((k & 1) << 7);
        if (r == k) {
            #pragma unroll
            for (int jj = 0; jj < 8; ++jj)
                reinterpret_cast<float4*>(rka + c0)[jj] =
                    make_float4(td[4*jj+0], td[4*jj+1], td[4*jj+2], td[4*jj+3]);
        }
        __syncthreads();
        if (t == 0) {
            float dd = 1.0f / rka[k];
            dsh[0] = dd;
            rka[k] += 1.0f;
        }
        __syncthreads();
        float d = dsh[0];
        if (r == k) {
            #pragma unroll
            for (int j = 0; j < 32; ++j) {
                float rv = rka[c0 + j];
                td[j] = (c0 + j == k) ? d : d * rv;
            }
        } else {
            float rkr = rka[r];
            float cd  = ((r < k) ? -rkr : rkr) * d;
            #pragma unroll
            for (int jj = 0; jj < 8; ++jj) {
                float4 rv = reinterpret_cast<const float4*>(rka + c0)[jj];
                td[4*jj+0] = fmaf(-cd, rv.x, td[4*jj+0]);
                td[4*jj+1] = fmaf(-cd, rv.y, td[4*jj+1]);
                td[4*jj+2] = fmaf(-cd, rv.z, td[4*jj+2]);
                td[4*jj+3] = fmaf(-cd, rv.w, td[4*jj+3]);
            }
        }
    }

    // ---- mu fragment + scratch writes ----
    {
        const float4* h4 = reinterpret_cast<const float4*>(hq + c0);
        float m0=0,m1=0,m2=0,m3=0;
        #pragma unroll
        for (int jj = 0; jj < 8; ++jj) {
            float4 hv = h4[jj];
            m0 = fmaf(td[4*jj+0], hv.x, m0);
            m1 = fmaf(td[4*jj+1], hv.y, m1);
            m2 = fmaf(td[4*jj+2], hv.z, m2);
            m3 = fmaf(td[4*jj+3], hv.w, m3);
        }
        float mur = qsum((m0+m1)+(m2+m3));
        if (q2t == 0) scb[SCR_MU + r] = mur;
    }
    {
        float4* dst = reinterpret_cast<float4*>(scb + SCR_TD + r*Mm + c0);
        #pragma unroll
        for (int jj = 0; jj < 8; ++jj)
            dst[jj] = make_float4(td[4*jj+0], td[4*jj+1], td[4*jj+2], td[4*jj+3]);
    }
}

// =============================== K2: serial loop, wave-specialized ===============================
// waves 0-3 (t<256): matvec role. qt = t&3 (32-col quarter), r = t>>2: rows r, r+64.
// waves 4-7: p role. t2 = t-256: qt = t2&3, a = t2>>2: p_{k-1}[a] from vb[prev].
// s / vb stored padded: word index(j) = (j>>5)*36 + (j&31)  (4 groups in disjoint banks).
__global__ void __launch_bounds__(NT2, 3)
qp_loop(const float* __restrict__ scr, long scrStride,
        const float* __restrict__ bg, float* __restrict__ out)
{
    __shared__ float sb[2][144];
    __shared__ float vb[2][144];
    const int t    = threadIdx.x;
    const int beta = blockIdx.x;
    const float* sc = scr + (size_t)beta * scrStride;

    float* outX = out + (size_t)beta * ((size_t)(NITER+1) * 2*Mm);
    float* outP = out + (size_t)NBATCH * ((size_t)(NITER+1) * 2*Mm)
                      + (size_t)beta * ((size_t)(NITER+1) * Nn);

    if (t < 256) {
        // ===================== matvec role =====================
        const int qt = t & 3, r = t >> 2;
        float td0[32], td1[32];
        {
            const float4* g0 = reinterpret_cast<const float4*>(sc + SCR_TD + r*Mm + 32*qt);
            const float4* g1 = reinterpret_cast<const float4*>(sc + SCR_TD + (r+64)*Mm + 32*qt);
            #pragma unroll
            for (int jj = 0; jj < 8; ++jj) {
                float4 v = g0[jj];
                td0[4*jj+0]=v.x; td0[4*jj+1]=v.y; td0[4*jj+2]=v.z; td0[4*jj+3]=v.w;
                float4 w = g1[jj];
                td1[4*jj+0]=w.x; td1[4*jj+1]=w.y; td1[4*jj+2]=w.z; td1[4*jj+3]=w.w;
            }
        }
        const float mu0 = sc[SCR_MU + r];
        const float mu1 = sc[SCR_MU + 64 + r];
        const float br0 = bg[(size_t)beta*Mm + r];
        const float br1 = bg[(size_t)beta*Mm + 64 + r];
        const int w0 = (r >> 5)*36 + (r & 31);
        const int w1 = 72 + w0;

        outX[t] = 0.f;                      // X0 = 0
        if (t < 144) sb[0][t] = 0.f;
        float sr0 = 0.f, sr1 = 0.f;
        __syncthreads();

        int cur = 0;
        for (int k = 1; k <= NITER; ++k) {
            const float4* s4 = reinterpret_cast<const float4*>(&sb[cur][36*qt]);
            float4 v[8];
            #pragma unroll
            for (int jj = 0; jj < 8; ++jj) v[jj] = s4[jj];
            float a00=0,a01=0,a02=0,a03=0, a10=0,a11=0,a12=0,a13=0;
            #pragma unroll
            for (int jj = 0; jj < 8; ++jj) {
                a00 = fmaf(td0[4*jj+0], v[jj].x, a00);
                a01 = fmaf(td0[4*jj+1], v[jj].y, a01);
                a02 = fmaf(td0[4*jj+2], v[jj].z, a02);
                a03 = fmaf(td0[4*jj+3], v[jj].w, a03);
                a10 = fmaf(td1[4*jj+0], v[jj].x, a10);
                a11 = fmaf(td1[4*jj+1], v[jj].y, a11);
                a12 = fmaf(td1[4*jj+2], v[jj].z, a12);
                a13 = fmaf(td1[4*jj+3], v[jj].w, a13);
            }
            float y0 = qsum((a00+a01)+(a02+a03));
            float y1 = qsum((a10+a11)+(a12+a13));

            float x1_0 = y0 + mu0;
            float x2_0 = fmaxf(fmaf(-2.0f, x1_0, sr0), 0.0f);
            sr0 = x1_0 + x2_0;
            float x1_1 = y1 + mu1;
            float x2_1 = fmaxf(fmaf(-2.0f, x1_1, sr1), 0.0f);
            sr1 = x1_1 + x2_1;

            const int dst = cur ^ 1;
            if      (qt == 0) sb[dst][w0] = sr0;
            else if (qt == 1) sb[dst][w1] = sr1;
            else if (qt == 2) vb[dst][w0] = x2_0 - br0;
            else              vb[dst][w1] = x2_1 - br1;

            float val = (qt == 0) ? x1_0 : (qt == 1) ? x2_0 : (qt == 2) ? x1_1 : x2_1;
            outX[(size_t)k*256 + ((qt & 1) << 7) + ((qt & 2) << 5) + r] = val;

            cur = dst;
            __syncthreads();
        }
    } else {
        // ===================== p role =====================
        const int t2 = t - 256;
        const int qt = t2 & 3, a = t2 >> 2;
        float ph[32];
        {
            const float4* pg = reinterpret_cast<const float4*>(sc + SCR_PH + a*Mm + 32*qt);
            #pragma unroll
            for (int jj = 0; jj < 8; ++jj) {
                float4 v = pg[jj];
                ph[4*jj+0]=v.x; ph[4*jj+1]=v.y; ph[4*jj+2]=v.z; ph[4*jj+3]=v.w;
            }
        }
        if (t2 < 128) {                     // vb[0] = X0_2 - b = -b
            int widx = (t2 >> 5)*36 + (t2 & 31);
            vb[0][widx] = -bg[(size_t)beta*Mm + t2];
        }
        __syncthreads();

        int cur = 0;
        for (int k = 1; k <= NITER; ++k) {
            const float4* v4 = reinterpret_cast<const float4*>(&vb[cur][36*qt]);
            float p0=0,p1=0,p2=0,p3=0;
            #pragma unroll
            for (int jj = 0; jj < 8; ++jj) {
                float4 vv = v4[jj];
                p0 = fmaf(ph[4*jj+0], vv.x, p0);
                p1 = fmaf(ph[4*jj+1], vv.y, p1);
                p2 = fmaf(ph[4*jj+2], vv.z, p2);
                p3 = fmaf(ph[4*jj+3], vv.w, p3);
            }
            float pp = qsum((p0+p1)+(p2+p3));
            if (qt == 0) outP[(size_t)(k-1)*Nn + a] = pp;
            cur ^= 1;
            __syncthreads();
        }
        // final p_{NITER} from vb[cur] (written before the last barrier)
        {
            const float4* v4 = reinterpret_cast<const float4*>(&vb[cur][36*qt]);
            float p0=0,p1=0,p2=0,p3=0;
            #pragma unroll
            for (int jj = 0; jj < 8; ++jj) {
                float4 vv = v4[jj];
                p0 = fmaf(ph[4*jj+0], vv.x, p0);
                p1 = fmaf(ph[4*jj+1], vv.y, p1);
                p2 = fmaf(ph[4*jj+2], vv.z, p2);
                p3 = fmaf(ph[4*jj+3], vv.w, p3);
            }
            float pp = qsum((p0+p1)+(p2+p3));
            if (qt == 0) outP[(size_t)NITER*Nn + a] = pp;
        }
    }
}

extern "C" void kernel_launch(void* const* d_in, const int* in_sizes, int n_in,
                              void* d_out, int out_size, void* d_ws, size_t ws_size,
                              hipStream_t stream)
{
    const float* q = (const float*)d_in[0];
    const float* b = (const float*)d_in[1];
    const float* P = (const float*)d_in[2];
    const float* H = (const float*)d_in[3];
    float* out = (float*)d_out;

    // scratch: prefer d_ws; else carve from the outP region (K2's outP writes land
    // there only after every block has loaded its own batch's scratch into regs).
    size_t need = (size_t)NBATCH * SCR_FLOATS * sizeof(float);
    float* scr;
    long stride;
    if (ws_size >= need) { scr = (float*)d_ws; stride = SCR_FLOATS; }
    else {
        scr = out + (size_t)NBATCH * ((size_t)(NITER+1) * 2*Mm);
        stride = (long)(NITER+1) * Nn;   // 64064 >= 24704
    }

    hipLaunchKernelGGL(qp_setup, dim3(NBATCH), dim3(NT1), 0, stream, q, b, P, H, scr, stride);
    hipLaunchKernelGGL(qp_loop,  dim3(NBATCH), dim3(NT2), 0, stream, scr, stride, b, out);
}

// Round 4
// 630.989 us; speedup vs baseline: 1.7706x; 1.0504x over previous
//
#include <hip/hip_runtime.h>

// QP fixed-point solver, 2-kernel. n=64, m=128, alpha=beta=1, iters=1000, bs=256.
//
// Algebra: A = [[tD,tD],[I-2tD,I-2tD]] so with s = X1+X2:
//   x1' = tD s + mu ;  x2' = relu(s - 2 x1') ;  p = pinvH (x2' - b)
// K1 (512 thr): setup (unchanged from round 3).
// K2 (768 thr, 12 waves): threads 0-511 matvec (1 row x 32-col quarter, v_pk_fma_f32),
//   threads 512-767 p-role one iteration behind. 1 barrier/iter, stride-36 padded s/vb.

#define NT1 512
#define NT2 768
#define Nn 64
#define Mm 128
#define NITER 1000
#define NBATCH 256

// scratch per batch (floats)
#define SCR_TD 0
#define SCR_MU 16384
#define SCR_PH 16512
#define SCR_FLOATS 24704

// K1 LDS offsets (floats)
#define OFF_HP   0        // H  [128][66]
#define OFF_WM   8448     // W = H*Pinv  [128][66]
#define OFF_PM   16896    // P -> Pinv   [64][66]
#define OFF_GM   21120    // G=H^T H -> Ginv [64][66]
#define OFF_ROWK 25344    // 256: dual-gj staging / GJ-128 pivot-row dbuf
#define OFF_DSH  25600
#define OFF_QV   25604
#define OFF_BV   25668
#define OFF_HQ   25796
#define OFF_PQ   25924
#define LDS1_FLOATS 25988   // 103,952 B

typedef float v2f __attribute__((ext_vector_type(2)));

// quad (4-lane) sum via DPP quad_perm: [1,0,3,2]=0xB1, [2,3,0,1]=0x4E
__device__ __forceinline__ float qsum(float x)
{
    int p;
    p = __builtin_amdgcn_update_dpp(0, __float_as_int(x), 0xB1, 0xF, 0xF, true);
    x += __int_as_float(p);
    p = __builtin_amdgcn_update_dpp(0, __float_as_int(x), 0x4E, 0xF, 0xF, true);
    x += __int_as_float(p);
    return x;
}

// =============================== K1: setup ===============================
__global__ void __launch_bounds__(NT1, 2)
qp_setup(const float* __restrict__ qg, const float* __restrict__ bg,
         const float* __restrict__ Pg, const float* __restrict__ Hg,
         float* __restrict__ scr, long scrStride)
{
    __shared__ float lds[LDS1_FLOATS];
    const int t    = threadIdx.x;
    const int beta = blockIdx.x;

    float* Hp   = lds + OFF_HP;
    float* Wm   = lds + OFF_WM;
    float* Pm   = lds + OFF_PM;
    float* Gm   = lds + OFF_GM;
    float* rowk = lds + OFF_ROWK;
    float* dsh  = lds + OFF_DSH;
    float* qv   = lds + OFF_QV;
    float* bv   = lds + OFF_BV;
    float* hq   = lds + OFF_HQ;
    float* pq   = lds + OFF_PQ;

    const float* Hgb = Hg + (size_t)beta * (Mm*Nn);
    const float* Pgb = Pg + (size_t)beta * (Nn*Nn);
    float* scb = scr + (size_t)beta * scrStride;

    // ---- stage inputs (float4 global reads, float2 LDS writes: stride 66) ----
    {
        const float4* Hg4 = reinterpret_cast<const float4*>(Hgb);
        for (int o4 = t; o4 < (Mm*Nn)/4; o4 += NT1) {
            float4 v = Hg4[o4];
            int i = o4 >> 4, n = (o4 & 15) << 2;
            float* d = Hp + i*66 + n;
            *reinterpret_cast<float2*>(d)     = make_float2(v.x, v.y);
            *reinterpret_cast<float2*>(d + 2) = make_float2(v.z, v.w);
        }
        const float4* Pg4 = reinterpret_cast<const float4*>(Pgb);
        for (int o4 = t; o4 < (Nn*Nn)/4; o4 += NT1) {
            float4 v = Pg4[o4];
            int i = o4 >> 4, n = (o4 & 15) << 2;
            float* d = Pm + i*66 + n;
            *reinterpret_cast<float2*>(d)     = make_float2(v.x, v.y);
            *reinterpret_cast<float2*>(d + 2) = make_float2(v.z, v.w);
        }
        if (t < Nn) qv[t] = qg[(size_t)beta*Nn + t];
        else if (t < Nn + Mm) bv[t - Nn] = bg[(size_t)beta*Mm + (t - Nn)];
    }
    __syncthreads();

    // ---- G = H^T H, register-tiled 4x2 ----
    {
        const int ra0 = (t >> 5) << 2;   // 4 rows
        const int cb0 = (t & 31) << 1;   // 2 cols
        float g00=0,g01=0,g10=0,g11=0,g20=0,g21=0,g30=0,g31=0;
        for (int i = 0; i < Mm; ++i) {
            const float* hr = Hp + i*66;
            float2 a01 = *reinterpret_cast<const float2*>(hr + ra0);
            float2 a23 = *reinterpret_cast<const float2*>(hr + ra0 + 2);
            float2 bb  = *reinterpret_cast<const float2*>(hr + cb0);
            g00 = fmaf(a01.x, bb.x, g00); g01 = fmaf(a01.x, bb.y, g01);
            g10 = fmaf(a01.y, bb.x, g10); g11 = fmaf(a01.y, bb.y, g11);
            g20 = fmaf(a23.x, bb.x, g20); g21 = fmaf(a23.x, bb.y, g21);
            g30 = fmaf(a23.y, bb.x, g30); g31 = fmaf(a23.y, bb.y, g31);
        }
        *reinterpret_cast<float2*>(Gm + (ra0+0)*66 + cb0) = make_float2(g00, g01);
        *reinterpret_cast<float2*>(Gm + (ra0+1)*66 + cb0) = make_float2(g10, g11);
        *reinterpret_cast<float2*>(Gm + (ra0+2)*66 + cb0) = make_float2(g20, g21);
        *reinterpret_cast<float2*>(Gm + (ra0+3)*66 + cb0) = make_float2(g30, g31);
    }
    __syncthreads();

    // ---- dual-interleaved Gauss-Jordan: Pm -> P^-1 and Gm -> G^-1 ----
    {
        float* rkP = rowk;
        float* ckP = rowk + 64;
        float* rkG = rowk + 128;
        float* ckG = rowk + 192;
        for (int k = 0; k < 64; ++k) {
            if (t < 64)        rkP[t]       = Pm[k*66 + t];
            else if (t < 128)  ckP[t - 64]  = Pm[(t-64)*66 + k];
            else if (t < 192)  rkG[t - 128] = Gm[k*66 + (t-128)];
            else if (t < 256)  ckG[t - 192] = Gm[(t-192)*66 + k];
            __syncthreads();
            float dP = 1.0f / rkP[k];
            float dG = 1.0f / rkG[k];
            #pragma unroll
            for (int ii = 0; ii < 16; ++ii) {
                int o = ii*NT1 + t;
                int rr = (o >> 6) & 63, cc = o & 63;
                float* A  = (ii < 8) ? Pm  : Gm;
                float* rk = (ii < 8) ? rkP : rkG;
                float* ck = (ii < 8) ? ckP : ckG;
                float d   = (ii < 8) ? dP  : dG;
                float cr = ck[rr];
                float rc = rk[cc];
                float v;
                if (rr == k)      v = (cc == k) ? d : d * rc;
                else if (cc == k) v = -d * cr;
                else              v = fmaf(-cr * d, rc, A[rr*66 + cc]);
                A[rr*66 + cc] = v;
            }
            __syncthreads();
        }
    }

    // ---- pq = Pinv q ----
    if (t < Nn) {
        const float2* pr = reinterpret_cast<const float2*>(Pm + t*66);
        const float2* q2 = reinterpret_cast<const float2*>(qv);
        float s0 = 0.f, s1 = 0.f;
        #pragma unroll
        for (int j = 0; j < 32; ++j) {
            float2 a = pr[j], b2 = q2[j];
            s0 = fmaf(a.x, b2.x, s0);
            s1 = fmaf(a.y, b2.y, s1);
        }
        pq[t] = s0 + s1;
    }
    __syncthreads();

    // ---- hoist H row (iw = t&127); W, pinvH, hq ----
    const int iw = t & 127;
    const int a0 = (t >> 7) << 4;   // 16 a's per thread
    float hrow[64];
    {
        const float2* hr2 = reinterpret_cast<const float2*>(Hp + iw*66);
        #pragma unroll
        for (int j = 0; j < 32; ++j) { float2 v = hr2[j]; hrow[2*j] = v.x; hrow[2*j+1] = v.y; }
    }
    for (int aa = 0; aa < 16; ++aa) {       // W[iw][a] = H row iw . Pinv row a
        int a = a0 + aa;
        const float2* pr = reinterpret_cast<const float2*>(Pm + a*66);
        float s0 = 0.f, s1 = 0.f;
        #pragma unroll
        for (int j = 0; j < 32; ++j) {
            float2 v = pr[j];
            s0 = fmaf(hrow[2*j],   v.x, s0);
            s1 = fmaf(hrow[2*j+1], v.y, s1);
        }
        Wm[iw*66 + a] = s0 + s1;
    }
    for (int aa = 0; aa < 16; ++aa) {       // pinvH[a][iw] = Ginv row a . H row iw
        int a = a0 + aa;
        const float2* gr = reinterpret_cast<const float2*>(Gm + a*66);
        float s0 = 0.f, s1 = 0.f;
        #pragma unroll
        for (int j = 0; j < 32; ++j) {
            float2 v = gr[j];
            s0 = fmaf(hrow[2*j],   v.x, s0);
            s1 = fmaf(hrow[2*j+1], v.y, s1);
        }
        scb[SCR_PH + a*Mm + iw] = s0 + s1;
    }
    if (t < Mm) {                           // hq[t] = H row t . pq - b  (hrow == row t)
        const float2* q2 = reinterpret_cast<const float2*>(pq);
        float s0 = 0.f, s1 = 0.f;
        #pragma unroll
        for (int j = 0; j < 32; ++j) {
            float2 v = q2[j];
            s0 = fmaf(hrow[2*j],   v.x, s0);
            s1 = fmaf(hrow[2*j+1], v.y, s1);
        }
        hq[t] = s0 + s1 - bv[t];
    }
    __syncthreads();

    // ---- S = I + W H^T into 32-wide register fragments ----
    const int r   = t >> 2;
    const int q2t = t & 3;
    const int c0  = q2t << 5;
    float td[32];
    {
        float wrow[64];
        const float2* wr2 = reinterpret_cast<const float2*>(Wm + r*66);
        #pragma unroll
        for (int j = 0; j < 32; ++j) { float2 v = wr2[j]; wrow[2*j] = v.x; wrow[2*j+1] = v.y; }
        for (int cc = 0; cc < 32; ++cc) {
            int c = c0 + cc;
            const float2* hc = reinterpret_cast<const float2*>(Hp + c*66);
            float s0 = 0.f, s1 = 0.f;
            #pragma unroll
            for (int j = 0; j < 32; ++j) {
                float2 v = hc[j];
                s0 = fmaf(wrow[2*j],   v.x, s0);
                s1 = fmaf(wrow[2*j+1], v.y, s1);
            }
            td[cc] = s0 + s1 + ((c == r) ? 1.0f : 0.0f);
        }
    }
    __syncthreads();

    // ---- in-register Gauss-Jordan of SPD (I+S): td -> tD fragment ----
    for (int k = 0; k < Mm; ++k) {
        float* rka = rowk + ((k & 1) << 7);
        if (r == k) {
            #pragma unroll
            for (int jj = 0; jj < 8; ++jj)
                reinterpret_cast<float4*>(rka + c0)[jj] =
                    make_float4(td[4*jj+0], td[4*jj+1], td[4*jj+2], td[4*jj+3]);
        }
        __syncthreads();
        if (t == 0) {
            float dd = 1.0f / rka[k];
            dsh[0] = dd;
            rka[k] += 1.0f;
        }
        __syncthreads();
        float d = dsh[0];
        if (r == k) {
            #pragma unroll
            for (int j = 0; j < 32; ++j) {
                float rv = rka[c0 + j];
                td[j] = (c0 + j == k) ? d : d * rv;
            }
        } else {
            float rkr = rka[r];
            float cd  = ((r < k) ? -rkr : rkr) * d;
            #pragma unroll
            for (int jj = 0; jj < 8; ++jj) {
                float4 rv = reinterpret_cast<const float4*>(rka + c0)[jj];
                td[4*jj+0] = fmaf(-cd, rv.x, td[4*jj+0]);
                td[4*jj+1] = fmaf(-cd, rv.y, td[4*jj+1]);
                td[4*jj+2] = fmaf(-cd, rv.z, td[4*jj+2]);
                td[4*jj+3] = fmaf(-cd, rv.w, td[4*jj+3]);
            }
        }
    }

    // ---- mu fragment + scratch writes ----
    {
        const float4* h4 = reinterpret_cast<const float4*>(hq + c0);
        float m0=0,m1=0,m2=0,m3=0;
        #pragma unroll
        for (int jj = 0; jj < 8; ++jj) {
            float4 hv = h4[jj];
            m0 = fmaf(td[4*jj+0], hv.x, m0);
            m1 = fmaf(td[4*jj+1], hv.y, m1);
            m2 = fmaf(td[4*jj+2], hv.z, m2);
            m3 = fmaf(td[4*jj+3], hv.w, m3);
        }
        float mur = qsum((m0+m1)+(m2+m3));
        if (q2t == 0) scb[SCR_MU + r] = mur;
    }
    {
        float4* dst = reinterpret_cast<float4*>(scb + SCR_TD + r*Mm + c0);
        #pragma unroll
        for (int jj = 0; jj < 8; ++jj)
            dst[jj] = make_float4(td[4*jj+0], td[4*jj+1], td[4*jj+2], td[4*jj+3]);
    }
}

// =============================== K2: serial loop ===============================
// 768 threads = 12 waves. t<512: matvec, qt=t&3 (32-col quarter), r=t>>2 (row).
// t>=512: p-role, one iteration behind. s/vb padded: idx(j) = (j>>5)*36 + (j&31).
__global__ void __launch_bounds__(NT2, 3)
qp_loop(const float* __restrict__ scr, long scrStride,
        const float* __restrict__ bg, float* __restrict__ out)
{
    __shared__ float sb[2][144];
    __shared__ float vb[2][144];
    const int t    = threadIdx.x;
    const int beta = blockIdx.x;
    const float* sc = scr + (size_t)beta * scrStride;

    float* outX = out + (size_t)beta * ((size_t)(NITER+1) * 2*Mm);
    float* outP = out + (size_t)NBATCH * ((size_t)(NITER+1) * 2*Mm)
                      + (size_t)beta * ((size_t)(NITER+1) * Nn);

    if (t < 512) {
        // ===================== matvec role =====================
        const int qt = t & 3, r = t >> 2;
        v2f td2[16];
        {
            const float4* g = reinterpret_cast<const float4*>(sc + SCR_TD + r*Mm + 32*qt);
            #pragma unroll
            for (int jj = 0; jj < 8; ++jj) {
                float4 v = g[jj];
                v2f lo; lo.x = v.x; lo.y = v.y;
                v2f hi; hi.x = v.z; hi.y = v.w;
                td2[2*jj] = lo; td2[2*jj+1] = hi;
            }
        }
        const float mur = sc[SCR_MU + r];
        const float br  = bg[(size_t)beta*Mm + r];
        const int w = (r >> 5)*36 + (r & 31);

        if (t < 256) outX[t] = 0.f;         // X0 = 0
        if (t < 144) sb[0][t] = 0.f;
        float sr = 0.f;
        __syncthreads();

        int cur = 0;
        for (int k = 1; k <= NITER; ++k) {
            const float4* s4 = reinterpret_cast<const float4*>(&sb[cur][36*qt]);
            v2f a0 = {0.f,0.f}, a1 = {0.f,0.f}, a2 = {0.f,0.f}, a3 = {0.f,0.f};
            #pragma unroll
            for (int jj = 0; jj < 8; ++jj) {
                float4 sv = s4[jj];
                v2f lo; lo.x = sv.x; lo.y = sv.y;
                v2f hi; hi.x = sv.z; hi.y = sv.w;
                if (jj & 1) {
                    a2 = __builtin_elementwise_fma(td2[2*jj],   lo, a2);
                    a3 = __builtin_elementwise_fma(td2[2*jj+1], hi, a3);
                } else {
                    a0 = __builtin_elementwise_fma(td2[2*jj],   lo, a0);
                    a1 = __builtin_elementwise_fma(td2[2*jj+1], hi, a1);
                }
            }
            v2f as = (a0 + a2) + (a1 + a3);
            float y = qsum(as.x + as.y);

            float x1 = y + mur;
            float x2 = fmaxf(fmaf(-2.0f, x1, sr), 0.0f);
            sr = x1 + x2;

            const int dst = cur ^ 1;
            if      (qt == 0) sb[dst][w] = sr;
            else if (qt == 1) vb[dst][w] = x2 - br;
            else if (qt == 2) outX[(size_t)k*256 + r] = x1;
            else              outX[(size_t)k*256 + 128 + r] = x2;

            cur = dst;
            __syncthreads();
        }
    } else {
        // ===================== p role =====================
        const int t2 = t - 512;
        const int qt = t2 & 3, a = t2 >> 2;
        v2f ph2[16];
        {
            const float4* g = reinterpret_cast<const float4*>(sc + SCR_PH + a*Mm + 32*qt);
            #pragma unroll
            for (int jj = 0; jj < 8; ++jj) {
                float4 v = g[jj];
                v2f lo; lo.x = v.x; lo.y = v.y;
                v2f hi; hi.x = v.z; hi.y = v.w;
                ph2[2*jj] = lo; ph2[2*jj+1] = hi;
            }
        }
        if (t2 < 128) {                     // vb[0] = X0_2 - b = -b
            vb[0][(t2 >> 5)*36 + (t2 & 31)] = -bg[(size_t)beta*Mm + t2];
        }
        __syncthreads();

        int cur = 0;
        for (int k = 1; k <= NITER; ++k) {
            const float4* v4 = reinterpret_cast<const float4*>(&vb[cur][36*qt]);
            v2f a0 = {0.f,0.f}, a1 = {0.f,0.f}, a2 = {0.f,0.f}, a3 = {0.f,0.f};
            #pragma unroll
            for (int jj = 0; jj < 8; ++jj) {
                float4 sv = v4[jj];
                v2f lo; lo.x = sv.x; lo.y = sv.y;
                v2f hi; hi.x = sv.z; hi.y = sv.w;
                if (jj & 1) {
                    a2 = __builtin_elementwise_fma(ph2[2*jj],   lo, a2);
                    a3 = __builtin_elementwise_fma(ph2[2*jj+1], hi, a3);
                } else {
                    a0 = __builtin_elementwise_fma(ph2[2*jj],   lo, a0);
                    a1 = __builtin_elementwise_fma(ph2[2*jj+1], hi, a1);
                }
            }
            v2f as = (a0 + a2) + (a1 + a3);
            float pp = qsum(as.x + as.y);
            if (qt == 0) outP[(size_t)(k-1)*Nn + a] = pp;
            cur ^= 1;
            __syncthreads();
        }
        // final p_{NITER} from vb[cur] (written before the last barrier)
        {
            const float4* v4 = reinterpret_cast<const float4*>(&vb[cur][36*qt]);
            v2f a0 = {0.f,0.f}, a1 = {0.f,0.f}, a2 = {0.f,0.f}, a3 = {0.f,0.f};
            #pragma unroll
            for (int jj = 0; jj < 8; ++jj) {
                float4 sv = v4[jj];
                v2f lo; lo.x = sv.x; lo.y = sv.y;
                v2f hi; hi.x = sv.z; hi.y = sv.w;
                if (jj & 1) {
                    a2 = __builtin_elementwise_fma(ph2[2*jj],   lo, a2);
                    a3 = __builtin_elementwise_fma(ph2[2*jj+1], hi, a3);
                } else {
                    a0 = __builtin_elementwise_fma(ph2[2*jj],   lo, a0);
                    a1 = __builtin_elementwise_fma(ph2[2*jj+1], hi, a1);
                }
            }
            v2f as = (a0 + a2) + (a1 + a3);
            float pp = qsum(as.x + as.y);
            if (qt == 0) outP[(size_t)NITER*Nn + a] = pp;
        }
    }
}

extern "C" void kernel_launch(void* const* d_in, const int* in_sizes, int n_in,
                              void* d_out, int out_size, void* d_ws, size_t ws_size,
                              hipStream_t stream)
{
    const float* q = (const float*)d_in[0];
    const float* b = (const float*)d_in[1];
    const float* P = (const float*)d_in[2];
    const float* H = (const float*)d_in[3];
    float* out = (float*)d_out;

    // scratch: prefer d_ws; else carve from the outP region (K2's outP writes land
    // there only after every block has loaded its own batch's scratch into regs).
    size_t need = (size_t)NBATCH * SCR_FLOATS * sizeof(float);
    float* scr;
    long stride;
    if (ws_size >= need) { scr = (float*)d_ws; stride = SCR_FLOATS; }
    else {
        scr = out + (size_t)NBATCH * ((size_t)(NITER+1) * 2*Mm);
        stride = (long)(NITER+1) * Nn;   // 64064 >= 24704
    }

    hipLaunchKernelGGL(qp_setup, dim3(NBATCH), dim3(NT1), 0, stream, q, b, P, H, scr, stride);
    hipLaunchKernelGGL(qp_loop,  dim3(NBATCH), dim3(NT2), 0, stream, scr, stride, b, out);
}

// Round 5
// 508.838 us; speedup vs baseline: 2.1957x; 1.2401x over previous
//
#include <hip/hip_runtime.h>

// QP fixed-point solver, 2-kernel. n=64, m=128, alpha=beta=1, iters=1000, bs=256.
//
// Algebra: A = [[tD,tD],[I-2tD,I-2tD]] so with s = X1+X2:
//   x1' = tD s + mu ;  x2' = relu(s - 2 x1') ;  p = pinvH (x2' - b)
// Woodbury: tD = (I + H P^-1 H^T)^-1 = I - H (P + H^T H)^-1 H^T = I - Y H^T.
// K1 (512 thr): G=H^T H; triple in-register GJ-64 inverts {P,G,R=P+G} (1 barrier/step,
//   pivot row staged dbuf, sweep symmetry); Y=H R^-1; pinvH=G^-1 H^T; tD; mu -> scratch.
// K2 (768 thr): waves 0-7 matvec with R=4 rows x C=8 cols/thread (reuse=4, LDS traffic
//   24KB/iter), DPP 16-lane reduce, writer lanes 12-15; waves 8-11 p-role 1 iter behind.

#define NT1 512
#define NT2 768
#define Nn 64
#define Mm 128
#define NITER 1000
#define NBATCH 256

// scratch per batch (floats)
#define SCR_TD 0          // tD row-major [128][128]
#define SCR_MU 16384      // mu [128]
#define SCR_PH 16512      // pinvH [64][128]
#define SCR_FLOATS 24704

// K1 LDS offsets (floats)
#define OFF_HP 0          // H [128][66]
#define OFF_YM 8448       // Y = H R^-1 [128][66]
#define OFF_GM 16896      // G -> G^-1 [64][66]
#define OFF_RM 21120      // R^-1 [64][66]
#define OFF_RS 25344      // pivot-row staging [2][3][64]
#define OFF_DS 25728      // pivot reciprocals [2][3] (+2 pad)
#define OFF_QV 25736
#define OFF_BV 25800
#define OFF_HQ 25928
#define OFF_PQ 26056
#define LDS1_FLOATS 26120  // 104,480 B

typedef float v2f __attribute__((ext_vector_type(2)));

// DPP add: ctrl must be a literal. quad_perm xor1=0xB1, xor2=0x4E; row_shr:4=0x114, :8=0x118
#define DPP_ADD(x, ctrl) ((x) + __int_as_float(__builtin_amdgcn_update_dpp( \
        0, __float_as_int(x), (ctrl), 0xF, 0xF, true)))

// =============================== K1: setup ===============================
__global__ void __launch_bounds__(NT1, 2)
qp_setup(const float* __restrict__ qg, const float* __restrict__ bg,
         const float* __restrict__ Pg, const float* __restrict__ Hg,
         float* __restrict__ scr, long scrStride)
{
    __shared__ float lds[LDS1_FLOATS];
    const int t    = threadIdx.x;
    const int beta = blockIdx.x;

    float* Hp  = lds + OFF_HP;
    float* Ym  = lds + OFF_YM;
    float* Gm  = lds + OFF_GM;
    float* Rm  = lds + OFF_RM;
    float* rs  = lds + OFF_RS;
    float* dsh = lds + OFF_DS;
    float* qv  = lds + OFF_QV;
    float* bv  = lds + OFF_BV;
    float* hq  = lds + OFF_HQ;
    float* pq  = lds + OFF_PQ;

    const float* Hgb = Hg + (size_t)beta * (Mm*Nn);
    const float* Pgb = Pg + (size_t)beta * (Nn*Nn);
    float* scb = scr + (size_t)beta * scrStride;

    // ---- stage H, q, b ----
    {
        const float4* Hg4 = reinterpret_cast<const float4*>(Hgb);
        for (int o4 = t; o4 < (Mm*Nn)/4; o4 += NT1) {
            float4 v = Hg4[o4];
            int i = o4 >> 4, n = (o4 & 15) << 2;
            float* d = Hp + i*66 + n;
            *reinterpret_cast<float2*>(d)     = make_float2(v.x, v.y);
            *reinterpret_cast<float2*>(d + 2) = make_float2(v.z, v.w);
        }
        if (t < Nn) qv[t] = qg[(size_t)beta*Nn + t];
        else if (t < Nn + Mm) bv[t - Nn] = bg[(size_t)beta*Mm + (t - Nn)];
    }
    __syncthreads();

    // ---- G = H^T H, register-tiled 4x2 -> Gm ----
    {
        const int ra0 = (t >> 5) << 2;
        const int cb0 = (t & 31) << 1;
        float g00=0,g01=0,g10=0,g11=0,g20=0,g21=0,g30=0,g31=0;
        for (int i = 0; i < Mm; ++i) {
            const float* hr = Hp + i*66;
            float2 a01 = *reinterpret_cast<const float2*>(hr + ra0);
            float2 a23 = *reinterpret_cast<const float2*>(hr + ra0 + 2);
            float2 bb  = *reinterpret_cast<const float2*>(hr + cb0);
            g00 = fmaf(a01.x, bb.x, g00); g01 = fmaf(a01.x, bb.y, g01);
            g10 = fmaf(a01.y, bb.x, g10); g11 = fmaf(a01.y, bb.y, g11);
            g20 = fmaf(a23.x, bb.x, g20); g21 = fmaf(a23.x, bb.y, g21);
            g30 = fmaf(a23.y, bb.x, g30); g31 = fmaf(a23.y, bb.y, g31);
        }
        *reinterpret_cast<float2*>(Gm + (ra0+0)*66 + cb0) = make_float2(g00, g01);
        *reinterpret_cast<float2*>(Gm + (ra0+1)*66 + cb0) = make_float2(g10, g11);
        *reinterpret_cast<float2*>(Gm + (ra0+2)*66 + cb0) = make_float2(g20, g21);
        *reinterpret_cast<float2*>(Gm + (ra0+3)*66 + cb0) = make_float2(g30, g31);
    }
    __syncthreads();

    // ---- fragments: thread owns row gr, cols gc0..gc0+8 of P, G, R ----
    const int gr  = t >> 3;
    const int gc0 = (t & 7) << 3;
    float fP[8], fG[8], fR[8];
    {
        float4 A = *reinterpret_cast<const float4*>(Pgb + gr*Nn + gc0);
        float4 B = *reinterpret_cast<const float4*>(Pgb + gr*Nn + gc0 + 4);
        fP[0]=A.x; fP[1]=A.y; fP[2]=A.z; fP[3]=A.w;
        fP[4]=B.x; fP[5]=B.y; fP[6]=B.z; fP[7]=B.w;
    }
    #pragma unroll
    for (int j = 0; j < 8; j += 2) {
        float2 v = *reinterpret_cast<const float2*>(Gm + gr*66 + gc0 + j);
        fG[j] = v.x; fG[j+1] = v.y;
    }
    #pragma unroll
    for (int j = 0; j < 8; ++j) fR[j] = fP[j] + fG[j];

    // ---- prestage pivot row 0 (+1 at col k trick; true reciprocal in dsh) ----
    if (gr == 0) {
        if (gc0 == 0) {
            dsh[0] = 1.0f / fP[0];
            dsh[1] = 1.0f / fG[0];
            dsh[2] = 1.0f / fR[0];
        }
        #pragma unroll
        for (int j = 0; j < 8; ++j) {
            float add = (gc0 + j == 0) ? 1.0f : 0.0f;
            rs[0*64 + gc0 + j] = fP[j] + add;
            rs[1*64 + gc0 + j] = fG[j] + add;
            rs[2*64 + gc0 + j] = fR[j] + add;
        }
    }
    __syncthreads();

    // ---- triple in-register GJ-64, 1 barrier/step ----
    #pragma unroll 2
    for (int k = 0; k < 64; ++k) {
        const int b = k & 1;
        const float* rP = rs + (b*3+0)*64;
        const float* rG = rs + (b*3+1)*64;
        const float* rR = rs + (b*3+2)*64;
        float vP[8], vG[8], vR[8];
        {
            float4 A = *reinterpret_cast<const float4*>(rP + gc0);
            float4 B = *reinterpret_cast<const float4*>(rP + gc0 + 4);
            vP[0]=A.x; vP[1]=A.y; vP[2]=A.z; vP[3]=A.w;
            vP[4]=B.x; vP[5]=B.y; vP[6]=B.z; vP[7]=B.w;
            A = *reinterpret_cast<const float4*>(rG + gc0);
            B = *reinterpret_cast<const float4*>(rG + gc0 + 4);
            vG[0]=A.x; vG[1]=A.y; vG[2]=A.z; vG[3]=A.w;
            vG[4]=B.x; vG[5]=B.y; vG[6]=B.z; vG[7]=B.w;
            A = *reinterpret_cast<const float4*>(rR + gc0);
            B = *reinterpret_cast<const float4*>(rR + gc0 + 4);
            vR[0]=A.x; vR[1]=A.y; vR[2]=A.z; vR[3]=A.w;
            vR[4]=B.x; vR[5]=B.y; vR[6]=B.z; vR[7]=B.w;
        }
        float rkrP = rP[gr], rkrG = rG[gr], rkrR = rR[gr];
        float dP = dsh[b*3+0], dG = dsh[b*3+1], dR = dsh[b*3+2];
        if (gr == k) {
            #pragma unroll
            for (int j = 0; j < 8; ++j) {
                bool diag = (gc0 + j == k);
                fP[j] = diag ? dP : fP[j]*dP;
                fG[j] = diag ? dG : fG[j]*dG;
                fR[j] = diag ? dR : fR[j]*dR;
            }
        } else {
            float sgn = (gr < k) ? -1.0f : 1.0f;     // sweep symmetry: A[r][k] = sgn*A[k][r]
            float cdP = sgn * rkrP * dP;
            float cdG = sgn * rkrG * dG;
            float cdR = sgn * rkrR * dR;
            #pragma unroll
            for (int j = 0; j < 8; ++j) {
                fP[j] = fmaf(-cdP, vP[j], fP[j]);
                fG[j] = fmaf(-cdG, vG[j], fG[j]);
                fR[j] = fmaf(-cdR, vR[j], fR[j]);
            }
        }
        if (gr == k+1) {
            const int bn = b ^ 1;
            if (((k+1) >> 3) == (t & 7)) {            // my chunk holds the next pivot
                const int ii = (k+1) & 7;
                float pP = fP[0], pG = fG[0], pR = fR[0];
                #pragma unroll
                for (int j = 1; j < 8; ++j) {
                    pP = (ii == j) ? fP[j] : pP;
                    pG = (ii == j) ? fG[j] : pG;
                    pR = (ii == j) ? fR[j] : pR;
                }
                dsh[bn*3+0] = 1.0f / pP;
                dsh[bn*3+1] = 1.0f / pG;
                dsh[bn*3+2] = 1.0f / pR;
            }
            #pragma unroll
            for (int j = 0; j < 8; ++j) {
                float add = (gc0 + j == k+1) ? 1.0f : 0.0f;
                rs[(bn*3+0)*64 + gc0 + j] = fP[j] + add;
                rs[(bn*3+1)*64 + gc0 + j] = fG[j] + add;
                rs[(bn*3+2)*64 + gc0 + j] = fR[j] + add;
            }
        }
        __syncthreads();
    }

    // ---- write G^-1, R^-1 to LDS; pq = P^-1 q from registers ----
    #pragma unroll
    for (int j = 0; j < 8; j += 2) {
        *reinterpret_cast<float2*>(Gm + gr*66 + gc0 + j) = make_float2(fG[j], fG[j+1]);
        *reinterpret_cast<float2*>(Rm + gr*66 + gc0 + j) = make_float2(fR[j], fR[j+1]);
    }
    {
        float s = 0.f;
        #pragma unroll
        for (int j = 0; j < 8; ++j) s = fmaf(fP[j], qv[gc0 + j], s);
        s = DPP_ADD(s, 0xB1);
        s = DPP_ADD(s, 0x4E);
        s = DPP_ADD(s, 0x114);            // 8-lane groups: lanes (t&7)>=4 hold full sums
        if ((t & 7) == 4) pq[gr] = s;
    }
    __syncthreads();

    // ---- Y = H R^-1 and pinvH = G^-1 H^T (hoisted H-row), hq ----
    const int iw = t & 127;
    const int a0 = (t >> 7) << 4;
    float hrow[64];
    #pragma unroll
    for (int j = 0; j < 32; ++j) {
        float2 v = reinterpret_cast<const float2*>(Hp + iw*66)[j];
        hrow[2*j] = v.x; hrow[2*j+1] = v.y;
    }
    for (int aa = 0; aa < 16; ++aa) {
        int a = a0 + aa;
        const float2* rr = reinterpret_cast<const float2*>(Rm + a*66);
        const float2* gg = reinterpret_cast<const float2*>(Gm + a*66);
        float sy0=0, sy1=0, sg0=0, sg1=0;
        #pragma unroll
        for (int j = 0; j < 32; ++j) {
            float2 rv = rr[j], gv = gg[j];
            sy0 = fmaf(hrow[2*j],   rv.x, sy0);
            sy1 = fmaf(hrow[2*j+1], rv.y, sy1);
            sg0 = fmaf(hrow[2*j],   gv.x, sg0);
            sg1 = fmaf(hrow[2*j+1], gv.y, sg1);
        }
        Ym[iw*66 + a] = sy0 + sy1;
        scb[SCR_PH + a*Mm + iw] = sg0 + sg1;
    }
    if (t < Mm) {
        const float2* q2 = reinterpret_cast<const float2*>(pq);
        float s0 = 0.f, s1 = 0.f;
        #pragma unroll
        for (int j = 0; j < 32; ++j) {
            float2 v = q2[j];
            s0 = fmaf(hrow[2*j],   v.x, s0);
            s1 = fmaf(hrow[2*j+1], v.y, s1);
        }
        hq[t] = s0 + s1 - bv[t];
    }
    __syncthreads();

    // ---- tD = I - Y H^T fragment (row r, 32 cols), mu, scratch write ----
    const int r   = t >> 2;
    const int c0f = (t & 3) << 5;
    v2f yr2[32];
    #pragma unroll
    for (int j = 0; j < 32; ++j) {
        float2 v = reinterpret_cast<const float2*>(Ym + r*66)[j];
        v2f w; w.x = v.x; w.y = v.y;
        yr2[j] = w;
    }
    float td[32];
    for (int cc = 0; cc < 32; ++cc) {
        int c = c0f + cc;
        const float2* hc = reinterpret_cast<const float2*>(Hp + c*66);
        v2f acc = {0.f, 0.f};
        #pragma unroll
        for (int j = 0; j < 32; ++j) {
            float2 hv = hc[j];
            v2f h2; h2.x = hv.x; h2.y = hv.y;
            acc = __builtin_elementwise_fma(yr2[j], h2, acc);
        }
        td[cc] = ((c == r) ? 1.0f : 0.0f) - (acc.x + acc.y);
    }
    {
        const float4* h4 = reinterpret_cast<const float4*>(hq + c0f);
        float m0=0,m1=0,m2=0,m3=0;
        #pragma unroll
        for (int jj = 0; jj < 8; ++jj) {
            float4 hv = h4[jj];
            m0 = fmaf(td[4*jj+0], hv.x, m0);
            m1 = fmaf(td[4*jj+1], hv.y, m1);
            m2 = fmaf(td[4*jj+2], hv.z, m2);
            m3 = fmaf(td[4*jj+3], hv.w, m3);
        }
        float mur = (m0+m1)+(m2+m3);
        mur = DPP_ADD(mur, 0xB1);
        mur = DPP_ADD(mur, 0x4E);
        if ((t & 3) == 0) scb[SCR_MU + r] = mur;
    }
    {
        float4* dst = reinterpret_cast<float4*>(scb + SCR_TD + (size_t)r*Mm + c0f);
        #pragma unroll
        for (int jj = 0; jj < 8; ++jj)
            dst[jj] = make_float4(td[4*jj+0], td[4*jj+1], td[4*jj+2], td[4*jj+3]);
    }
}

// =============================== K2: serial loop ===============================
// s / vb padded: element j at word (j>>3)*12 + (j&7)  (16-chunk stride 12 => b128-aligned,
// exactly 2-way bank aliasing = free). Fragment: 4 rows x 8 cols per thread.
__device__ __forceinline__ void frag_load(v2f (&f)[4][4], const float* __restrict__ base,
                                          int rowstart, int c)
{
    #pragma unroll
    for (int i = 0; i < 4; ++i) {
        const float4* gp = reinterpret_cast<const float4*>(base + (size_t)(rowstart+i)*Mm + c*8);
        float4 A = gp[0], B = gp[1];
        f[i][0].x=A.x; f[i][0].y=A.y; f[i][1].x=A.z; f[i][1].y=A.w;
        f[i][2].x=B.x; f[i][2].y=B.y; f[i][3].x=B.z; f[i][3].y=B.w;
    }
}

__device__ __forceinline__ void dots4(const v2f (&f)[4][4], const float* __restrict__ buf,
                                      int c, float& y0, float& y1, float& y2, float& y3)
{
    const float4* sp = reinterpret_cast<const float4*>(buf + c*12);
    float4 A = sp[0], B = sp[1];
    v2f s0, s1, s2, s3;
    s0.x=A.x; s0.y=A.y; s1.x=A.z; s1.y=A.w;
    s2.x=B.x; s2.y=B.y; s3.x=B.z; s3.y=B.w;
    v2f a0={0.f,0.f}, a1={0.f,0.f}, a2={0.f,0.f}, a3={0.f,0.f};
    a0 = __builtin_elementwise_fma(f[0][0], s0, a0);
    a0 = __builtin_elementwise_fma(f[0][1], s1, a0);
    a0 = __builtin_elementwise_fma(f[0][2], s2, a0);
    a0 = __builtin_elementwise_fma(f[0][3], s3, a0);
    a1 = __builtin_elementwise_fma(f[1][0], s0, a1);
    a1 = __builtin_elementwise_fma(f[1][1], s1, a1);
    a1 = __builtin_elementwise_fma(f[1][2], s2, a1);
    a1 = __builtin_elementwise_fma(f[1][3], s3, a1);
    a2 = __builtin_elementwise_fma(f[2][0], s0, a2);
    a2 = __builtin_elementwise_fma(f[2][1], s1, a2);
    a2 = __builtin_elementwise_fma(f[2][2], s2, a2);
    a2 = __builtin_elementwise_fma(f[2][3], s3, a2);
    a3 = __builtin_elementwise_fma(f[3][0], s0, a3);
    a3 = __builtin_elementwise_fma(f[3][1], s1, a3);
    a3 = __builtin_elementwise_fma(f[3][2], s2, a3);
    a3 = __builtin_elementwise_fma(f[3][3], s3, a3);
    y0 = a0.x + a0.y; y1 = a1.x + a1.y; y2 = a2.x + a2.y; y3 = a3.x + a3.y;
    // 16-lane reduce: xor1, xor2 (quad sums), shr:4, shr:8 -> lanes 12..15 hold full sums
    y0 = DPP_ADD(y0, 0xB1); y0 = DPP_ADD(y0, 0x4E); y0 = DPP_ADD(y0, 0x114); y0 = DPP_ADD(y0, 0x118);
    y1 = DPP_ADD(y1, 0xB1); y1 = DPP_ADD(y1, 0x4E); y1 = DPP_ADD(y1, 0x114); y1 = DPP_ADD(y1, 0x118);
    y2 = DPP_ADD(y2, 0xB1); y2 = DPP_ADD(y2, 0x4E); y2 = DPP_ADD(y2, 0x114); y2 = DPP_ADD(y2, 0x118);
    y3 = DPP_ADD(y3, 0xB1); y3 = DPP_ADD(y3, 0x4E); y3 = DPP_ADD(y3, 0x114); y3 = DPP_ADD(y3, 0x118);
}

__global__ void __launch_bounds__(NT2, 3)
qp_loop(const float* __restrict__ scr, long scrStride,
        const float* __restrict__ bg, float* __restrict__ out)
{
    __shared__ float sb[2][192];
    __shared__ float vb[2][192];
    const int t    = threadIdx.x;
    const int beta = blockIdx.x;
    const float* sc = scr + (size_t)beta * scrStride;

    float* outX = out + (size_t)beta * ((size_t)(NITER+1) * 2*Mm);
    float* outP = out + (size_t)NBATCH * ((size_t)(NITER+1) * 2*Mm)
                      + (size_t)beta * ((size_t)(NITER+1) * Nn);

    const int lane = t & 63;
    const int g  = lane >> 4;      // rowgrp within wave
    const int c  = lane & 15;      // colpos
    const int wi = c - 12;         // writer sub-row (valid when >= 0)

    if (t < 512) {
        // ===================== matvec role =====================
        const int w  = t >> 6;
        const int r0 = w*16 + g*4;
        v2f td2[4][4];
        frag_load(td2, sc + SCR_TD, r0, c);
        const int wr = r0 + (wi < 0 ? 0 : wi);
        float mur = 0.f, br = 0.f, sr = 0.f;
        if (wi >= 0) {
            mur = sc[SCR_MU + wr];
            br  = bg[(size_t)beta*Mm + wr];
        }
        const int ww = (wr >> 3)*12 + (wr & 7);
        if (t < 192) sb[0][t] = 0.f;
        if (t < 256) outX[t] = 0.f;          // X0 = 0
        __syncthreads();

        int cur = 0;
        #pragma unroll 2
        for (int k = 1; k <= NITER; ++k) {
            float y0, y1, y2, y3;
            dots4(td2, sb[cur], c, y0, y1, y2, y3);
            const int dst = cur ^ 1;
            if (wi >= 0) {
                float y  = (wi == 0) ? y0 : (wi == 1) ? y1 : (wi == 2) ? y2 : y3;
                float x1 = y + mur;
                float x2 = fmaxf(fmaf(-2.0f, x1, sr), 0.0f);
                sr = x1 + x2;
                sb[dst][ww] = sr;
                vb[dst][ww] = x2 - br;
                outX[(size_t)k*256 + wr]       = x1;
                outX[(size_t)k*256 + 128 + wr] = x2;
            }
            cur = dst;
            __syncthreads();
        }
    } else {
        // ===================== p role (one iteration behind) =====================
        const int t2  = t - 512;
        const int w2  = t2 >> 6;
        const int a0r = w2*16 + g*4;
        v2f ph2[4][4];
        frag_load(ph2, sc + SCR_PH, a0r, c);
        const int wa = a0r + (wi < 0 ? 0 : wi);
        if (t2 < 128) vb[0][(t2 >> 3)*12 + (t2 & 7)] = -bg[(size_t)beta*Mm + t2];
        __syncthreads();

        int cur = 0;
        #pragma unroll 2
        for (int k = 1; k <= NITER; ++k) {
            float y0, y1, y2, y3;
            dots4(ph2, vb[cur], c, y0, y1, y2, y3);
            if (wi >= 0) {
                float pp = (wi == 0) ? y0 : (wi == 1) ? y1 : (wi == 2) ? y2 : y3;
                outP[(size_t)(k-1)*Nn + wa] = pp;
            }
            cur ^= 1;
            __syncthreads();
        }
        {
            float y0, y1, y2, y3;
            dots4(ph2, vb[cur], c, y0, y1, y2, y3);
            if (wi >= 0) {
                float pp = (wi == 0) ? y0 : (wi == 1) ? y1 : (wi == 2) ? y2 : y3;
                outP[(size_t)NITER*Nn + wa] = pp;
            }
        }
    }
}

extern "C" void kernel_launch(void* const* d_in, const int* in_sizes, int n_in,
                              void* d_out, int out_size, void* d_ws, size_t ws_size,
                              hipStream_t stream)
{
    const float* q = (const float*)d_in[0];
    const float* b = (const float*)d_in[1];
    const float* P = (const float*)d_in[2];
    const float* H = (const float*)d_in[3];
    float* out = (float*)d_out;

    // scratch: prefer d_ws; else carve from the outP region (K2 reads its own batch's
    // scratch at init before that block's outP writes begin; blocks touch only their
    // own batch region).
    size_t need = (size_t)NBATCH * SCR_FLOATS * sizeof(float);
    float* scr;
    long stride;
    if (ws_size >= need) { scr = (float*)d_ws; stride = SCR_FLOATS; }
    else {
        scr = out + (size_t)NBATCH * ((size_t)(NITER+1) * 2*Mm);
        stride = (long)(NITER+1) * Nn;   // 64064 >= 24704
    }

    hipLaunchKernelGGL(qp_setup, dim3(NBATCH), dim3(NT1), 0, stream, q, b, P, H, scr, stride);
    hipLaunchKernelGGL(qp_loop,  dim3(NBATCH), dim3(NT2), 0, stream, scr, stride, b, out);
}

// Round 6
// 454.491 us; speedup vs baseline: 2.4582x; 1.1196x over previous
//
#include <hip/hip_runtime.h>

// QP fixed-point solver, 2-kernel. n=64, m=128, alpha=beta=1, iters=1000, bs=256.
//
// Algebra: A = [[tD,tD],[I-2tD,I-2tD]] so with s = X1+X2:
//   x1' = tD s + mu ;  x2' = relu(s - 2 x1') ;  p = pinvH (x2' - b)
// Woodbury: tD = I - H (P + H^T H)^-1 H^T.
// K1 (512 thr): G=H^T H; triple in-register GJ-64 of {P,G,R=P+G}; Y=H R^-1;
//   pinvH=G^-1 H^T; tD; mu -> scratch.  (unchanged, verified)
// K2 (768 thr): R=2 rows x C=16 cols per thread. ds_read_b128 = 128B distinct
//   data (8 segs x 8-way broadcast, conflict-free); v4f pk-fma; 3-DPP 8-lane
//   reduce; writer lanes (l&7)==4,5. Waves 0-7 matvec, 8-11 p (1 iter behind).

#define NT1 512
#define NT2 768
#define Nn 64
#define Mm 128
#define NITER 1000
#define NBATCH 256

// scratch per batch (floats)
#define SCR_TD 0          // tD row-major [128][128]
#define SCR_MU 16384      // mu [128]
#define SCR_PH 16512      // pinvH [64][128]
#define SCR_FLOATS 24704

// K1 LDS offsets (floats)
#define OFF_HP 0          // H [128][66]
#define OFF_YM 8448       // Y = H R^-1 [128][66]
#define OFF_GM 16896      // G -> G^-1 [64][66]
#define OFF_RM 21120      // R^-1 [64][66]
#define OFF_RS 25344      // pivot-row staging [2][3][64]
#define OFF_DS 25728      // pivot reciprocals [2][3] (+2 pad)
#define OFF_QV 25736
#define OFF_BV 25800
#define OFF_HQ 25928
#define OFF_PQ 26056
#define LDS1_FLOATS 26120  // 104,480 B

typedef float v2f __attribute__((ext_vector_type(2)));
typedef float v4f __attribute__((ext_vector_type(4)));

// DPP add: quad_perm xor1=0xB1, xor2=0x4E; row_shr:4=0x114, row_shr:8=0x118
#define DPP_ADD(x, ctrl) ((x) + __int_as_float(__builtin_amdgcn_update_dpp( \
        0, __float_as_int(x), (ctrl), 0xF, 0xF, true)))

// =============================== K1: setup ===============================
__global__ void __launch_bounds__(NT1, 2)
qp_setup(const float* __restrict__ qg, const float* __restrict__ bg,
         const float* __restrict__ Pg, const float* __restrict__ Hg,
         float* __restrict__ scr, long scrStride)
{
    __shared__ float lds[LDS1_FLOATS];
    const int t    = threadIdx.x;
    const int beta = blockIdx.x;

    float* Hp  = lds + OFF_HP;
    float* Ym  = lds + OFF_YM;
    float* Gm  = lds + OFF_GM;
    float* Rm  = lds + OFF_RM;
    float* rs  = lds + OFF_RS;
    float* dsh = lds + OFF_DS;
    float* qv  = lds + OFF_QV;
    float* bv  = lds + OFF_BV;
    float* hq  = lds + OFF_HQ;
    float* pq  = lds + OFF_PQ;

    const float* Hgb = Hg + (size_t)beta * (Mm*Nn);
    const float* Pgb = Pg + (size_t)beta * (Nn*Nn);
    float* scb = scr + (size_t)beta * scrStride;

    // ---- stage H, q, b ----
    {
        const float4* Hg4 = reinterpret_cast<const float4*>(Hgb);
        for (int o4 = t; o4 < (Mm*Nn)/4; o4 += NT1) {
            float4 v = Hg4[o4];
            int i = o4 >> 4, n = (o4 & 15) << 2;
            float* d = Hp + i*66 + n;
            *reinterpret_cast<float2*>(d)     = make_float2(v.x, v.y);
            *reinterpret_cast<float2*>(d + 2) = make_float2(v.z, v.w);
        }
        if (t < Nn) qv[t] = qg[(size_t)beta*Nn + t];
        else if (t < Nn + Mm) bv[t - Nn] = bg[(size_t)beta*Mm + (t - Nn)];
    }
    __syncthreads();

    // ---- G = H^T H, register-tiled 4x2 -> Gm ----
    {
        const int ra0 = (t >> 5) << 2;
        const int cb0 = (t & 31) << 1;
        float g00=0,g01=0,g10=0,g11=0,g20=0,g21=0,g30=0,g31=0;
        for (int i = 0; i < Mm; ++i) {
            const float* hr = Hp + i*66;
            float2 a01 = *reinterpret_cast<const float2*>(hr + ra0);
            float2 a23 = *reinterpret_cast<const float2*>(hr + ra0 + 2);
            float2 bb  = *reinterpret_cast<const float2*>(hr + cb0);
            g00 = fmaf(a01.x, bb.x, g00); g01 = fmaf(a01.x, bb.y, g01);
            g10 = fmaf(a01.y, bb.x, g10); g11 = fmaf(a01.y, bb.y, g11);
            g20 = fmaf(a23.x, bb.x, g20); g21 = fmaf(a23.x, bb.y, g21);
            g30 = fmaf(a23.y, bb.x, g30); g31 = fmaf(a23.y, bb.y, g31);
        }
        *reinterpret_cast<float2*>(Gm + (ra0+0)*66 + cb0) = make_float2(g00, g01);
        *reinterpret_cast<float2*>(Gm + (ra0+1)*66 + cb0) = make_float2(g10, g11);
        *reinterpret_cast<float2*>(Gm + (ra0+2)*66 + cb0) = make_float2(g20, g21);
        *reinterpret_cast<float2*>(Gm + (ra0+3)*66 + cb0) = make_float2(g30, g31);
    }
    __syncthreads();

    // ---- fragments: thread owns row gr, cols gc0..gc0+8 of P, G, R ----
    const int gr  = t >> 3;
    const int gc0 = (t & 7) << 3;
    float fP[8], fG[8], fR[8];
    {
        float4 A = *reinterpret_cast<const float4*>(Pgb + gr*Nn + gc0);
        float4 B = *reinterpret_cast<const float4*>(Pgb + gr*Nn + gc0 + 4);
        fP[0]=A.x; fP[1]=A.y; fP[2]=A.z; fP[3]=A.w;
        fP[4]=B.x; fP[5]=B.y; fP[6]=B.z; fP[7]=B.w;
    }
    #pragma unroll
    for (int j = 0; j < 8; j += 2) {
        float2 v = *reinterpret_cast<const float2*>(Gm + gr*66 + gc0 + j);
        fG[j] = v.x; fG[j+1] = v.y;
    }
    #pragma unroll
    for (int j = 0; j < 8; ++j) fR[j] = fP[j] + fG[j];

    // ---- prestage pivot row 0 ----
    if (gr == 0) {
        if (gc0 == 0) {
            dsh[0] = 1.0f / fP[0];
            dsh[1] = 1.0f / fG[0];
            dsh[2] = 1.0f / fR[0];
        }
        #pragma unroll
        for (int j = 0; j < 8; ++j) {
            float add = (gc0 + j == 0) ? 1.0f : 0.0f;
            rs[0*64 + gc0 + j] = fP[j] + add;
            rs[1*64 + gc0 + j] = fG[j] + add;
            rs[2*64 + gc0 + j] = fR[j] + add;
        }
    }
    __syncthreads();

    // ---- triple in-register GJ-64, 1 barrier/step ----
    #pragma unroll 2
    for (int k = 0; k < 64; ++k) {
        const int b = k & 1;
        const float* rP = rs + (b*3+0)*64;
        const float* rG = rs + (b*3+1)*64;
        const float* rR = rs + (b*3+2)*64;
        float vP[8], vG[8], vR[8];
        {
            float4 A = *reinterpret_cast<const float4*>(rP + gc0);
            float4 B = *reinterpret_cast<const float4*>(rP + gc0 + 4);
            vP[0]=A.x; vP[1]=A.y; vP[2]=A.z; vP[3]=A.w;
            vP[4]=B.x; vP[5]=B.y; vP[6]=B.z; vP[7]=B.w;
            A = *reinterpret_cast<const float4*>(rG + gc0);
            B = *reinterpret_cast<const float4*>(rG + gc0 + 4);
            vG[0]=A.x; vG[1]=A.y; vG[2]=A.z; vG[3]=A.w;
            vG[4]=B.x; vG[5]=B.y; vG[6]=B.z; vG[7]=B.w;
            A = *reinterpret_cast<const float4*>(rR + gc0);
            B = *reinterpret_cast<const float4*>(rR + gc0 + 4);
            vR[0]=A.x; vR[1]=A.y; vR[2]=A.z; vR[3]=A.w;
            vR[4]=B.x; vR[5]=B.y; vR[6]=B.z; vR[7]=B.w;
        }
        float rkrP = rP[gr], rkrG = rG[gr], rkrR = rR[gr];
        float dP = dsh[b*3+0], dG = dsh[b*3+1], dR = dsh[b*3+2];
        if (gr == k) {
            #pragma unroll
            for (int j = 0; j < 8; ++j) {
                bool diag = (gc0 + j == k);
                fP[j] = diag ? dP : fP[j]*dP;
                fG[j] = diag ? dG : fG[j]*dG;
                fR[j] = diag ? dR : fR[j]*dR;
            }
        } else {
            float sgn = (gr < k) ? -1.0f : 1.0f;
            float cdP = sgn * rkrP * dP;
            float cdG = sgn * rkrG * dG;
            float cdR = sgn * rkrR * dR;
            #pragma unroll
            for (int j = 0; j < 8; ++j) {
                fP[j] = fmaf(-cdP, vP[j], fP[j]);
                fG[j] = fmaf(-cdG, vG[j], fG[j]);
                fR[j] = fmaf(-cdR, vR[j], fR[j]);
            }
        }
        if (gr == k+1) {
            const int bn = b ^ 1;
            if (((k+1) >> 3) == (t & 7)) {
                const int ii = (k+1) & 7;
                float pP = fP[0], pG = fG[0], pR = fR[0];
                #pragma unroll
                for (int j = 1; j < 8; ++j) {
                    pP = (ii == j) ? fP[j] : pP;
                    pG = (ii == j) ? fG[j] : pG;
                    pR = (ii == j) ? fR[j] : pR;
                }
                dsh[bn*3+0] = 1.0f / pP;
                dsh[bn*3+1] = 1.0f / pG;
                dsh[bn*3+2] = 1.0f / pR;
            }
            #pragma unroll
            for (int j = 0; j < 8; ++j) {
                float add = (gc0 + j == k+1) ? 1.0f : 0.0f;
                rs[(bn*3+0)*64 + gc0 + j] = fP[j] + add;
                rs[(bn*3+1)*64 + gc0 + j] = fG[j] + add;
                rs[(bn*3+2)*64 + gc0 + j] = fR[j] + add;
            }
        }
        __syncthreads();
    }

    // ---- write G^-1, R^-1 to LDS; pq = P^-1 q from registers ----
    #pragma unroll
    for (int j = 0; j < 8; j += 2) {
        *reinterpret_cast<float2*>(Gm + gr*66 + gc0 + j) = make_float2(fG[j], fG[j+1]);
        *reinterpret_cast<float2*>(Rm + gr*66 + gc0 + j) = make_float2(fR[j], fR[j+1]);
    }
    {
        float s = 0.f;
        #pragma unroll
        for (int j = 0; j < 8; ++j) s = fmaf(fP[j], qv[gc0 + j], s);
        s = DPP_ADD(s, 0xB1);
        s = DPP_ADD(s, 0x4E);
        s = DPP_ADD(s, 0x114);
        if ((t & 7) == 4) pq[gr] = s;
    }
    __syncthreads();

    // ---- Y = H R^-1 and pinvH = G^-1 H^T (hoisted H-row), hq ----
    const int iw = t & 127;
    const int a0 = (t >> 7) << 4;
    float hrow[64];
    #pragma unroll
    for (int j = 0; j < 32; ++j) {
        float2 v = reinterpret_cast<const float2*>(Hp + iw*66)[j];
        hrow[2*j] = v.x; hrow[2*j+1] = v.y;
    }
    for (int aa = 0; aa < 16; ++aa) {
        int a = a0 + aa;
        const float2* rr = reinterpret_cast<const float2*>(Rm + a*66);
        const float2* gg = reinterpret_cast<const float2*>(Gm + a*66);
        float sy0=0, sy1=0, sg0=0, sg1=0;
        #pragma unroll
        for (int j = 0; j < 32; ++j) {
            float2 rv = rr[j], gv = gg[j];
            sy0 = fmaf(hrow[2*j],   rv.x, sy0);
            sy1 = fmaf(hrow[2*j+1], rv.y, sy1);
            sg0 = fmaf(hrow[2*j],   gv.x, sg0);
            sg1 = fmaf(hrow[2*j+1], gv.y, sg1);
        }
        Ym[iw*66 + a] = sy0 + sy1;
        scb[SCR_PH + a*Mm + iw] = sg0 + sg1;
    }
    if (t < Mm) {
        const float2* q2 = reinterpret_cast<const float2*>(pq);
        float s0 = 0.f, s1 = 0.f;
        #pragma unroll
        for (int j = 0; j < 32; ++j) {
            float2 v = q2[j];
            s0 = fmaf(hrow[2*j],   v.x, s0);
            s1 = fmaf(hrow[2*j+1], v.y, s1);
        }
        hq[t] = s0 + s1 - bv[t];
    }
    __syncthreads();

    // ---- tD = I - Y H^T fragment (row r, 32 cols), mu, scratch write ----
    const int r   = t >> 2;
    const int c0f = (t & 3) << 5;
    v2f yr2[32];
    #pragma unroll
    for (int j = 0; j < 32; ++j) {
        float2 v = reinterpret_cast<const float2*>(Ym + r*66)[j];
        v2f w; w.x = v.x; w.y = v.y;
        yr2[j] = w;
    }
    float td[32];
    for (int cc = 0; cc < 32; ++cc) {
        int c = c0f + cc;
        const float2* hc = reinterpret_cast<const float2*>(Hp + c*66);
        v2f acc = {0.f, 0.f};
        #pragma unroll
        for (int j = 0; j < 32; ++j) {
            float2 hv = hc[j];
            v2f h2; h2.x = hv.x; h2.y = hv.y;
            acc = __builtin_elementwise_fma(yr2[j], h2, acc);
        }
        td[cc] = ((c == r) ? 1.0f : 0.0f) - (acc.x + acc.y);
    }
    {
        const float4* h4 = reinterpret_cast<const float4*>(hq + c0f);
        float m0=0,m1=0,m2=0,m3=0;
        #pragma unroll
        for (int jj = 0; jj < 8; ++jj) {
            float4 hv = h4[jj];
            m0 = fmaf(td[4*jj+0], hv.x, m0);
            m1 = fmaf(td[4*jj+1], hv.y, m1);
            m2 = fmaf(td[4*jj+2], hv.z, m2);
            m3 = fmaf(td[4*jj+3], hv.w, m3);
        }
        float mur = (m0+m1)+(m2+m3);
        mur = DPP_ADD(mur, 0xB1);
        mur = DPP_ADD(mur, 0x4E);
        if ((t & 3) == 0) scb[SCR_MU + r] = mur;
    }
    {
        float4* dst = reinterpret_cast<float4*>(scb + SCR_TD + (size_t)r*Mm + c0f);
        #pragma unroll
        for (int jj = 0; jj < 8; ++jj)
            dst[jj] = make_float4(td[4*jj+0], td[4*jj+1], td[4*jj+2], td[4*jj+3]);
    }
}

// =============================== K2: serial loop ===============================
// Thread tile: 2 rows x 16 cols. col-group g = lane&7 -> cols g*16..g*16+15.
// ds_read_b128: per instr 8 distinct contiguous 16B segments (x8 broadcast) =
// 128B, all 32 banks once -> conflict-free full BW. 8-lane reduce = 3 DPP.
// Writer lanes (lane&7)==4 (row r0) and ==5 (row r1) keep sr state and do all
// LDS/global writes. Waves 0-7 matvec, waves 8-11 p (one iteration behind).
__device__ __forceinline__ void dot2x16(const v4f (&f0)[4], const v4f (&f1)[4],
                                        const float* __restrict__ buf, int g,
                                        float& y0, float& y1)
{
    const v4f* s4 = reinterpret_cast<const v4f*>(buf + g*16);
    v4f sv0 = s4[0], sv1 = s4[1], sv2 = s4[2], sv3 = s4[3];
    v4f a0 = {0.f,0.f,0.f,0.f}, b0 = a0, a1 = a0, b1 = a0;
    a0 = __builtin_elementwise_fma(f0[0], sv0, a0);
    b0 = __builtin_elementwise_fma(f0[1], sv1, b0);
    a0 = __builtin_elementwise_fma(f0[2], sv2, a0);
    b0 = __builtin_elementwise_fma(f0[3], sv3, b0);
    a1 = __builtin_elementwise_fma(f1[0], sv0, a1);
    b1 = __builtin_elementwise_fma(f1[1], sv1, b1);
    a1 = __builtin_elementwise_fma(f1[2], sv2, a1);
    b1 = __builtin_elementwise_fma(f1[3], sv3, b1);
    v4f c0 = a0 + b0, c1 = a1 + b1;
    v2f h0 = __builtin_shufflevector(c0, c0, 0, 1) + __builtin_shufflevector(c0, c0, 2, 3);
    v2f h1 = __builtin_shufflevector(c1, c1, 0, 1) + __builtin_shufflevector(c1, c1, 2, 3);
    y0 = h0.x + h0.y;
    y1 = h1.x + h1.y;
    // 8-lane reduce: quad sums then shr:4 -> lanes (l&7)>=4 hold full sums
    y0 = DPP_ADD(y0, 0xB1); y0 = DPP_ADD(y0, 0x4E); y0 = DPP_ADD(y0, 0x114);
    y1 = DPP_ADD(y1, 0xB1); y1 = DPP_ADD(y1, 0x4E); y1 = DPP_ADD(y1, 0x114);
}

__global__ void __launch_bounds__(NT2, 3)
qp_loop(const float* __restrict__ scr, long scrStride,
        const float* __restrict__ bg, float* __restrict__ out)
{
    __shared__ float sb[2][128];
    __shared__ float vb[2][128];
    const int t    = threadIdx.x;
    const int beta = blockIdx.x;
    const float* sc = scr + (size_t)beta * scrStride;

    float* outX = out + (size_t)beta * ((size_t)(NITER+1) * 2*Mm);
    float* outP = out + (size_t)NBATCH * ((size_t)(NITER+1) * 2*Mm)
                      + (size_t)beta * ((size_t)(NITER+1) * Nn);

    const int lane = t & 63;
    const int g    = lane & 7;        // col-group
    const bool wr0 = (g == 4);
    const bool wr1 = (g == 5);

    if (t < 512) {
        // ===================== matvec role =====================
        const int rg = t >> 3;         // 0..63 row-pair
        const int r0 = rg*2, r1 = r0 + 1;
        v4f f0[4], f1[4];
        {
            const v4f* g0p = reinterpret_cast<const v4f*>(sc + SCR_TD + (size_t)r0*Mm + g*16);
            const v4f* g1p = reinterpret_cast<const v4f*>(sc + SCR_TD + (size_t)r1*Mm + g*16);
            #pragma unroll
            for (int j = 0; j < 4; ++j) { f0[j] = g0p[j]; f1[j] = g1p[j]; }
        }
        const int myr = wr0 ? r0 : r1;
        float mur = 0.f, br = 0.f, sr = 0.f;
        if (wr0 || wr1) {
            mur = sc[SCR_MU + myr];
            br  = bg[(size_t)beta*Mm + myr];
        }
        if (t < 128) sb[0][t] = 0.f;     // s0 = 0
        if (t < 256) outX[t]  = 0.f;     // X0 = 0
        __syncthreads();

        int cur = 0;
        for (int k = 1; k <= NITER; ++k) {
            float y0, y1;
            dot2x16(f0, f1, sb[cur], g, y0, y1);
            const int dst = cur ^ 1;
            if (wr0 || wr1) {
                float y  = wr0 ? y0 : y1;
                float x1 = y + mur;
                float x2 = fmaxf(fmaf(-2.0f, x1, sr), 0.0f);
                sr = x1 + x2;
                sb[dst][myr] = sr;
                vb[dst][myr] = x2 - br;
                outX[(size_t)k*256 + myr]       = x1;
                outX[(size_t)k*256 + 128 + myr] = x2;
            }
            cur = dst;
            __syncthreads();
        }
    } else {
        // ===================== p role (one iteration behind) =====================
        const int t2 = t - 512;        // 0..255
        const int ag = t2 >> 3;        // 0..31 row-pair of pinvH
        const int a0r = ag*2, a1r = a0r + 1;
        v4f f0[4], f1[4];
        {
            const v4f* g0p = reinterpret_cast<const v4f*>(sc + SCR_PH + (size_t)a0r*Mm + g*16);
            const v4f* g1p = reinterpret_cast<const v4f*>(sc + SCR_PH + (size_t)a1r*Mm + g*16);
            #pragma unroll
            for (int j = 0; j < 4; ++j) { f0[j] = g0p[j]; f1[j] = g1p[j]; }
        }
        const int mya = wr0 ? a0r : a1r;
        if (t2 < 128) vb[0][t2] = -bg[(size_t)beta*Mm + t2];   // X0_2 - b
        __syncthreads();

        int cur = 0;
        for (int k = 1; k <= NITER; ++k) {
            float y0, y1;
            dot2x16(f0, f1, vb[cur], g, y0, y1);
            if (wr0 || wr1) outP[(size_t)(k-1)*Nn + mya] = wr0 ? y0 : y1;
            cur ^= 1;
            __syncthreads();
        }
        {   // final p_{NITER} from vb[cur] (written before the last barrier)
            float y0, y1;
            dot2x16(f0, f1, vb[cur], g, y0, y1);
            if (wr0 || wr1) outP[(size_t)NITER*Nn + mya] = wr0 ? y0 : y1;
        }
    }
}

extern "C" void kernel_launch(void* const* d_in, const int* in_sizes, int n_in,
                              void* d_out, int out_size, void* d_ws, size_t ws_size,
                              hipStream_t stream)
{
    const float* q = (const float*)d_in[0];
    const float* b = (const float*)d_in[1];
    const float* P = (const float*)d_in[2];
    const float* H = (const float*)d_in[3];
    float* out = (float*)d_out;

    // scratch: prefer d_ws; else carve from the outP region (each block reads only
    // its own batch's scratch before writing that batch's outP region).
    size_t need = (size_t)NBATCH * SCR_FLOATS * sizeof(float);
    float* scr;
    long stride;
    if (ws_size >= need) { scr = (float*)d_ws; stride = SCR_FLOATS; }
    else {
        scr = out + (size_t)NBATCH * ((size_t)(NITER+1) * 2*Mm);
        stride = (long)(NITER+1) * Nn;   // 64064 >= 24704
    }

    hipLaunchKernelGGL(qp_setup, dim3(NBATCH), dim3(NT1), 0, stream, q, b, P, H, scr, stride);
    hipLaunchKernelGGL(qp_loop,  dim3(NBATCH), dim3(NT2), 0, stream, scr, stride, b, out);
}

// Round 7
// 435.155 us; speedup vs baseline: 2.5675x; 1.0444x over previous
//
#include <hip/hip_runtime.h>

// QP fixed-point solver, 2-kernel. n=64, m=128, alpha=beta=1, iters=1000, bs=256.
//
// Algebra: A = [[tD,tD],[I-2tD,I-2tD]] so with s = X1+X2:
//   x1' = tD s + mu ;  x2' = relu(s - 2 x1') ;  p = pinvH (x2' - b)
// Woodbury: tD = I - H (P + H^T H)^-1 H^T.
// K1 (512 thr): G=H^T H; triple in-register GJ-64 of {P,G,R=P+G}; Y=H R^-1;
//   pinvH=G^-1 H^T; tD; mu -> scratch.  (unchanged, verified)
// K2 (768 thr): 2 rows x 16 cols per thread. s/vb stored with group-stride 20
//   (word(j) = (j>>4)*20 + (j&15)): the 8 col-group bases hit banks
//   {0,20,8,28,16,4,24,12} -> every ds_read_b128 covers all 32 banks once,
//   conflict-free. Loop barrier = s_waitcnt lgkmcnt(0) + s_barrier (no vmcnt
//   drain -> global-store retirement off the critical path).

#define NT1 512
#define NT2 768
#define Nn 64
#define Mm 128
#define NITER 1000
#define NBATCH 256

// scratch per batch (floats)
#define SCR_TD 0          // tD row-major [128][128]
#define SCR_MU 16384      // mu [128]
#define SCR_PH 16512      // pinvH [64][128]
#define SCR_FLOATS 24704

// K1 LDS offsets (floats)
#define OFF_HP 0          // H [128][66]
#define OFF_YM 8448       // Y = H R^-1 [128][66]
#define OFF_GM 16896      // G -> G^-1 [64][66]
#define OFF_RM 21120      // R^-1 [64][66]
#define OFF_RS 25344      // pivot-row staging [2][3][64]
#define OFF_DS 25728      // pivot reciprocals [2][3] (+2 pad)
#define OFF_QV 25736
#define OFF_BV 25800
#define OFF_HQ 25928
#define OFF_PQ 26056
#define LDS1_FLOATS 26120  // 104,480 B

typedef float v2f __attribute__((ext_vector_type(2)));
typedef float v4f __attribute__((ext_vector_type(4)));

// DPP add: quad_perm xor1=0xB1, xor2=0x4E; row_shr:4=0x114
#define DPP_ADD(x, ctrl) ((x) + __int_as_float(__builtin_amdgcn_update_dpp( \
        0, __float_as_int(x), (ctrl), 0xF, 0xF, true)))

// s/vb padded word index
#define SW(j) ((((j) >> 4) * 20) + ((j) & 15))

// =============================== K1: setup ===============================
__global__ void __launch_bounds__(NT1, 2)
qp_setup(const float* __restrict__ qg, const float* __restrict__ bg,
         const float* __restrict__ Pg, const float* __restrict__ Hg,
         float* __restrict__ scr, long scrStride)
{
    __shared__ float lds[LDS1_FLOATS];
    const int t    = threadIdx.x;
    const int beta = blockIdx.x;

    float* Hp  = lds + OFF_HP;
    float* Ym  = lds + OFF_YM;
    float* Gm  = lds + OFF_GM;
    float* Rm  = lds + OFF_RM;
    float* rs  = lds + OFF_RS;
    float* dsh = lds + OFF_DS;
    float* qv  = lds + OFF_QV;
    float* bv  = lds + OFF_BV;
    float* hq  = lds + OFF_HQ;
    float* pq  = lds + OFF_PQ;

    const float* Hgb = Hg + (size_t)beta * (Mm*Nn);
    const float* Pgb = Pg + (size_t)beta * (Nn*Nn);
    float* scb = scr + (size_t)beta * scrStride;

    // ---- stage H, q, b ----
    {
        const float4* Hg4 = reinterpret_cast<const float4*>(Hgb);
        for (int o4 = t; o4 < (Mm*Nn)/4; o4 += NT1) {
            float4 v = Hg4[o4];
            int i = o4 >> 4, n = (o4 & 15) << 2;
            float* d = Hp + i*66 + n;
            *reinterpret_cast<float2*>(d)     = make_float2(v.x, v.y);
            *reinterpret_cast<float2*>(d + 2) = make_float2(v.z, v.w);
        }
        if (t < Nn) qv[t] = qg[(size_t)beta*Nn + t];
        else if (t < Nn + Mm) bv[t - Nn] = bg[(size_t)beta*Mm + (t - Nn)];
    }
    __syncthreads();

    // ---- G = H^T H, register-tiled 4x2 -> Gm ----
    {
        const int ra0 = (t >> 5) << 2;
        const int cb0 = (t & 31) << 1;
        float g00=0,g01=0,g10=0,g11=0,g20=0,g21=0,g30=0,g31=0;
        for (int i = 0; i < Mm; ++i) {
            const float* hr = Hp + i*66;
            float2 a01 = *reinterpret_cast<const float2*>(hr + ra0);
            float2 a23 = *reinterpret_cast<const float2*>(hr + ra0 + 2);
            float2 bb  = *reinterpret_cast<const float2*>(hr + cb0);
            g00 = fmaf(a01.x, bb.x, g00); g01 = fmaf(a01.x, bb.y, g01);
            g10 = fmaf(a01.y, bb.x, g10); g11 = fmaf(a01.y, bb.y, g11);
            g20 = fmaf(a23.x, bb.x, g20); g21 = fmaf(a23.x, bb.y, g21);
            g30 = fmaf(a23.y, bb.x, g30); g31 = fmaf(a23.y, bb.y, g31);
        }
        *reinterpret_cast<float2*>(Gm + (ra0+0)*66 + cb0) = make_float2(g00, g01);
        *reinterpret_cast<float2*>(Gm + (ra0+1)*66 + cb0) = make_float2(g10, g11);
        *reinterpret_cast<float2*>(Gm + (ra0+2)*66 + cb0) = make_float2(g20, g21);
        *reinterpret_cast<float2*>(Gm + (ra0+3)*66 + cb0) = make_float2(g30, g31);
    }
    __syncthreads();

    // ---- fragments: thread owns row gr, cols gc0..gc0+8 of P, G, R ----
    const int gr  = t >> 3;
    const int gc0 = (t & 7) << 3;
    float fP[8], fG[8], fR[8];
    {
        float4 A = *reinterpret_cast<const float4*>(Pgb + gr*Nn + gc0);
        float4 B = *reinterpret_cast<const float4*>(Pgb + gr*Nn + gc0 + 4);
        fP[0]=A.x; fP[1]=A.y; fP[2]=A.z; fP[3]=A.w;
        fP[4]=B.x; fP[5]=B.y; fP[6]=B.z; fP[7]=B.w;
    }
    #pragma unroll
    for (int j = 0; j < 8; j += 2) {
        float2 v = *reinterpret_cast<const float2*>(Gm + gr*66 + gc0 + j);
        fG[j] = v.x; fG[j+1] = v.y;
    }
    #pragma unroll
    for (int j = 0; j < 8; ++j) fR[j] = fP[j] + fG[j];

    // ---- prestage pivot row 0 ----
    if (gr == 0) {
        if (gc0 == 0) {
            dsh[0] = 1.0f / fP[0];
            dsh[1] = 1.0f / fG[0];
            dsh[2] = 1.0f / fR[0];
        }
        #pragma unroll
        for (int j = 0; j < 8; ++j) {
            float add = (gc0 + j == 0) ? 1.0f : 0.0f;
            rs[0*64 + gc0 + j] = fP[j] + add;
            rs[1*64 + gc0 + j] = fG[j] + add;
            rs[2*64 + gc0 + j] = fR[j] + add;
        }
    }
    __syncthreads();

    // ---- triple in-register GJ-64, 1 barrier/step ----
    #pragma unroll 2
    for (int k = 0; k < 64; ++k) {
        const int b = k & 1;
        const float* rP = rs + (b*3+0)*64;
        const float* rG = rs + (b*3+1)*64;
        const float* rR = rs + (b*3+2)*64;
        float vP[8], vG[8], vR[8];
        {
            float4 A = *reinterpret_cast<const float4*>(rP + gc0);
            float4 B = *reinterpret_cast<const float4*>(rP + gc0 + 4);
            vP[0]=A.x; vP[1]=A.y; vP[2]=A.z; vP[3]=A.w;
            vP[4]=B.x; vP[5]=B.y; vP[6]=B.z; vP[7]=B.w;
            A = *reinterpret_cast<const float4*>(rG + gc0);
            B = *reinterpret_cast<const float4*>(rG + gc0 + 4);
            vG[0]=A.x; vG[1]=A.y; vG[2]=A.z; vG[3]=A.w;
            vG[4]=B.x; vG[5]=B.y; vG[6]=B.z; vG[7]=B.w;
            A = *reinterpret_cast<const float4*>(rR + gc0);
            B = *reinterpret_cast<const float4*>(rR + gc0 + 4);
            vR[0]=A.x; vR[1]=A.y; vR[2]=A.z; vR[3]=A.w;
            vR[4]=B.x; vR[5]=B.y; vR[6]=B.z; vR[7]=B.w;
        }
        float rkrP = rP[gr], rkrG = rG[gr], rkrR = rR[gr];
        float dP = dsh[b*3+0], dG = dsh[b*3+1], dR = dsh[b*3+2];
        if (gr == k) {
            #pragma unroll
            for (int j = 0; j < 8; ++j) {
                bool diag = (gc0 + j == k);
                fP[j] = diag ? dP : fP[j]*dP;
                fG[j] = diag ? dG : fG[j]*dG;
                fR[j] = diag ? dR : fR[j]*dR;
            }
        } else {
            float sgn = (gr < k) ? -1.0f : 1.0f;
            float cdP = sgn * rkrP * dP;
            float cdG = sgn * rkrG * dG;
            float cdR = sgn * rkrR * dR;
            #pragma unroll
            for (int j = 0; j < 8; ++j) {
                fP[j] = fmaf(-cdP, vP[j], fP[j]);
                fG[j] = fmaf(-cdG, vG[j], fG[j]);
                fR[j] = fmaf(-cdR, vR[j], fR[j]);
            }
        }
        if (gr == k+1) {
            const int bn = b ^ 1;
            if (((k+1) >> 3) == (t & 7)) {
                const int ii = (k+1) & 7;
                float pP = fP[0], pG = fG[0], pR = fR[0];
                #pragma unroll
                for (int j = 1; j < 8; ++j) {
                    pP = (ii == j) ? fP[j] : pP;
                    pG = (ii == j) ? fG[j] : pG;
                    pR = (ii == j) ? fR[j] : pR;
                }
                dsh[bn*3+0] = 1.0f / pP;
                dsh[bn*3+1] = 1.0f / pG;
                dsh[bn*3+2] = 1.0f / pR;
            }
            #pragma unroll
            for (int j = 0; j < 8; ++j) {
                float add = (gc0 + j == k+1) ? 1.0f : 0.0f;
                rs[(bn*3+0)*64 + gc0 + j] = fP[j] + add;
                rs[(bn*3+1)*64 + gc0 + j] = fG[j] + add;
                rs[(bn*3+2)*64 + gc0 + j] = fR[j] + add;
            }
        }
        __syncthreads();
    }

    // ---- write G^-1, R^-1 to LDS; pq = P^-1 q from registers ----
    #pragma unroll
    for (int j = 0; j < 8; j += 2) {
        *reinterpret_cast<float2*>(Gm + gr*66 + gc0 + j) = make_float2(fG[j], fG[j+1]);
        *reinterpret_cast<float2*>(Rm + gr*66 + gc0 + j) = make_float2(fR[j], fR[j+1]);
    }
    {
        float s = 0.f;
        #pragma unroll
        for (int j = 0; j < 8; ++j) s = fmaf(fP[j], qv[gc0 + j], s);
        s = DPP_ADD(s, 0xB1);
        s = DPP_ADD(s, 0x4E);
        s = DPP_ADD(s, 0x114);
        if ((t & 7) == 4) pq[gr] = s;
    }
    __syncthreads();

    // ---- Y = H R^-1 and pinvH = G^-1 H^T (hoisted H-row), hq ----
    const int iw = t & 127;
    const int a0 = (t >> 7) << 4;
    float hrow[64];
    #pragma unroll
    for (int j = 0; j < 32; ++j) {
        float2 v = reinterpret_cast<const float2*>(Hp + iw*66)[j];
        hrow[2*j] = v.x; hrow[2*j+1] = v.y;
    }
    for (int aa = 0; aa < 16; ++aa) {
        int a = a0 + aa;
        const float2* rr = reinterpret_cast<const float2*>(Rm + a*66);
        const float2* gg = reinterpret_cast<const float2*>(Gm + a*66);
        float sy0=0, sy1=0, sg0=0, sg1=0;
        #pragma unroll
        for (int j = 0; j < 32; ++j) {
            float2 rv = rr[j], gv = gg[j];
            sy0 = fmaf(hrow[2*j],   rv.x, sy0);
            sy1 = fmaf(hrow[2*j+1], rv.y, sy1);
            sg0 = fmaf(hrow[2*j],   gv.x, sg0);
            sg1 = fmaf(hrow[2*j+1], gv.y, sg1);
        }
        Ym[iw*66 + a] = sy0 + sy1;
        scb[SCR_PH + a*Mm + iw] = sg0 + sg1;
    }
    if (t < Mm) {
        const float2* q2 = reinterpret_cast<const float2*>(pq);
        float s0 = 0.f, s1 = 0.f;
        #pragma unroll
        for (int j = 0; j < 32; ++j) {
            float2 v = q2[j];
            s0 = fmaf(hrow[2*j],   v.x, s0);
            s1 = fmaf(hrow[2*j+1], v.y, s1);
        }
        hq[t] = s0 + s1 - bv[t];
    }
    __syncthreads();

    // ---- tD = I - Y H^T fragment (row r, 32 cols), mu, scratch write ----
    const int r   = t >> 2;
    const int c0f = (t & 3) << 5;
    v2f yr2[32];
    #pragma unroll
    for (int j = 0; j < 32; ++j) {
        float2 v = reinterpret_cast<const float2*>(Ym + r*66)[j];
        v2f w; w.x = v.x; w.y = v.y;
        yr2[j] = w;
    }
    float td[32];
    for (int cc = 0; cc < 32; ++cc) {
        int c = c0f + cc;
        const float2* hc = reinterpret_cast<const float2*>(Hp + c*66);
        v2f acc = {0.f, 0.f};
        #pragma unroll
        for (int j = 0; j < 32; ++j) {
            float2 hv = hc[j];
            v2f h2; h2.x = hv.x; h2.y = hv.y;
            acc = __builtin_elementwise_fma(yr2[j], h2, acc);
        }
        td[cc] = ((c == r) ? 1.0f : 0.0f) - (acc.x + acc.y);
    }
    {
        const float4* h4 = reinterpret_cast<const float4*>(hq + c0f);
        float m0=0,m1=0,m2=0,m3=0;
        #pragma unroll
        for (int jj = 0; jj < 8; ++jj) {
            float4 hv = h4[jj];
            m0 = fmaf(td[4*jj+0], hv.x, m0);
            m1 = fmaf(td[4*jj+1], hv.y, m1);
            m2 = fmaf(td[4*jj+2], hv.z, m2);
            m3 = fmaf(td[4*jj+3], hv.w, m3);
        }
        float mur = (m0+m1)+(m2+m3);
        mur = DPP_ADD(mur, 0xB1);
        mur = DPP_ADD(mur, 0x4E);
        if ((t & 3) == 0) scb[SCR_MU + r] = mur;
    }
    {
        float4* dst = reinterpret_cast<float4*>(scb + SCR_TD + (size_t)r*Mm + c0f);
        #pragma unroll
        for (int jj = 0; jj < 8; ++jj)
            dst[jj] = make_float4(td[4*jj+0], td[4*jj+1], td[4*jj+2], td[4*jj+3]);
    }
}

// =============================== K2: serial loop ===============================
__device__ __forceinline__ void dot2x16(const v4f (&f0)[4], const v4f (&f1)[4],
                                        const float* __restrict__ gbuf,
                                        float& y0, float& y1)
{
    const v4f* s4 = reinterpret_cast<const v4f*>(gbuf);
    v4f sv0 = s4[0], sv1 = s4[1], sv2 = s4[2], sv3 = s4[3];
    v4f a0 = {0.f,0.f,0.f,0.f}, b0 = a0, a1 = a0, b1 = a0;
    a0 = __builtin_elementwise_fma(f0[0], sv0, a0);
    b0 = __builtin_elementwise_fma(f0[1], sv1, b0);
    a0 = __builtin_elementwise_fma(f0[2], sv2, a0);
    b0 = __builtin_elementwise_fma(f0[3], sv3, b0);
    a1 = __builtin_elementwise_fma(f1[0], sv0, a1);
    b1 = __builtin_elementwise_fma(f1[1], sv1, b1);
    a1 = __builtin_elementwise_fma(f1[2], sv2, a1);
    b1 = __builtin_elementwise_fma(f1[3], sv3, b1);
    v4f c0 = a0 + b0, c1 = a1 + b1;
    v2f h0 = __builtin_shufflevector(c0, c0, 0, 1) + __builtin_shufflevector(c0, c0, 2, 3);
    v2f h1 = __builtin_shufflevector(c1, c1, 0, 1) + __builtin_shufflevector(c1, c1, 2, 3);
    y0 = h0.x + h0.y;
    y1 = h1.x + h1.y;
    // 8-lane reduce: quad sums then shr:4 -> lanes (l&7)>=4 hold full sums
    y0 = DPP_ADD(y0, 0xB1); y0 = DPP_ADD(y0, 0x4E); y0 = DPP_ADD(y0, 0x114);
    y1 = DPP_ADD(y1, 0xB1); y1 = DPP_ADD(y1, 0x4E); y1 = DPP_ADD(y1, 0x114);
}

#define LOOP_BARRIER() do { \
    asm volatile("s_waitcnt lgkmcnt(0)" ::: "memory"); \
    __builtin_amdgcn_s_barrier(); \
} while (0)

__global__ void __launch_bounds__(NT2, 3)
qp_loop(const float* __restrict__ scr, long scrStride,
        const float* __restrict__ bg, float* __restrict__ out)
{
    __shared__ float sb[2][160];
    __shared__ float vb[2][160];
    const int t    = threadIdx.x;
    const int beta = blockIdx.x;
    const float* sc = scr + (size_t)beta * scrStride;

    float* outX = out + (size_t)beta * ((size_t)(NITER+1) * 2*Mm);
    float* outP = out + (size_t)NBATCH * ((size_t)(NITER+1) * 2*Mm)
                      + (size_t)beta * ((size_t)(NITER+1) * Nn);

    const int lane = t & 63;
    const int g    = lane & 7;        // col-group: cols g*16..g*16+15
    const bool wr0 = (g == 4);
    const bool wr1 = (g == 5);

    if (t < 512) {
        // ===================== matvec role =====================
        const int rg = t >> 3;         // 0..63 row-pair
        const int r0 = rg*2, r1 = r0 + 1;
        v4f f0[4], f1[4];
        {
            const v4f* g0p = reinterpret_cast<const v4f*>(sc + SCR_TD + (size_t)r0*Mm + g*16);
            const v4f* g1p = reinterpret_cast<const v4f*>(sc + SCR_TD + (size_t)r1*Mm + g*16);
            #pragma unroll
            for (int j = 0; j < 4; ++j) { f0[j] = g0p[j]; f1[j] = g1p[j]; }
        }
        const int myr = wr0 ? r0 : r1;
        float mur = 0.f, br = 0.f, sr = 0.f;
        if (wr0 || wr1) {
            mur = sc[SCR_MU + myr];
            br  = bg[(size_t)beta*Mm + myr];
        }
        const int ww = SW(myr);
        if (t < 128) sb[0][SW(t)] = 0.f;   // s0 = 0
        if (t < 256) outX[t] = 0.f;        // X0 = 0
        __syncthreads();

        int cur = 0;
        float* px = outX + 256;            // k = 1 row base
        for (int k = 1; k <= NITER; ++k) {
            float y0, y1;
            dot2x16(f0, f1, &sb[cur][g*20], y0, y1);
            const int dst = cur ^ 1;
            if (wr0 || wr1) {
                float y  = wr0 ? y0 : y1;
                float x1 = y + mur;
                float x2 = fmaxf(fmaf(-2.0f, x1, sr), 0.0f);
                sr = x1 + x2;
                sb[dst][ww] = sr;
                vb[dst][ww] = x2 - br;
                px[myr]       = x1;
                px[128 + myr] = x2;
            }
            LOOP_BARRIER();
            px += 256;
            cur = dst;
        }
    } else {
        // ===================== p role (one iteration behind) =====================
        const int t2 = t - 512;        // 0..255
        const int ag = t2 >> 3;        // 0..31 row-pair of pinvH
        const int a0r = ag*2, a1r = a0r + 1;
        v4f f0[4], f1[4];
        {
            const v4f* g0p = reinterpret_cast<const v4f*>(sc + SCR_PH + (size_t)a0r*Mm + g*16);
            const v4f* g1p = reinterpret_cast<const v4f*>(sc + SCR_PH + (size_t)a1r*Mm + g*16);
            #pragma unroll
            for (int j = 0; j < 4; ++j) { f0[j] = g0p[j]; f1[j] = g1p[j]; }
        }
        const int mya = wr0 ? a0r : a1r;
        if (t2 < 128) vb[0][SW(t2)] = -bg[(size_t)beta*Mm + t2];   // X0_2 - b
        __syncthreads();

        int cur = 0;
        float* pout = outP;            // k-1 = 0 row base
        for (int k = 1; k <= NITER; ++k) {
            float y0, y1;
            dot2x16(f0, f1, &vb[cur][g*20], y0, y1);
            if (wr0 || wr1) pout[mya] = wr0 ? y0 : y1;
            LOOP_BARRIER();
            pout += Nn;
            cur ^= 1;
        }
        {   // final p_{NITER} from vb[cur] (written before the last barrier)
            float y0, y1;
            dot2x16(f0, f1, &vb[cur][g*20], y0, y1);
            if (wr0 || wr1) pout[mya] = wr0 ? y0 : y1;
        }
    }
}

extern "C" void kernel_launch(void* const* d_in, const int* in_sizes, int n_in,
                              void* d_out, int out_size, void* d_ws, size_t ws_size,
                              hipStream_t stream)
{
    const float* q = (const float*)d_in[0];
    const float* b = (const float*)d_in[1];
    const float* P = (const float*)d_in[2];
    const float* H = (const float*)d_in[3];
    float* out = (float*)d_out;

    // scratch: prefer d_ws; else carve from the outP region (each block reads only
    // its own batch's scratch before writing that batch's outP region).
    size_t need = (size_t)NBATCH * SCR_FLOATS * sizeof(float);
    float* scr;
    long stride;
    if (ws_size >= need) { scr = (float*)d_ws; stride = SCR_FLOATS; }
    else {
        scr = out + (size_t)NBATCH * ((size_t)(NITER+1) * 2*Mm);
        stride = (long)(NITER+1) * Nn;   // 64064 >= 24704
    }

    hipLaunchKernelGGL(qp_setup, dim3(NBATCH), dim3(NT1), 0, stream, q, b, P, H, scr, stride);
    hipLaunchKernelGGL(qp_loop,  dim3(NBATCH), dim3(NT2), 0, stream, scr, stride, b, out);
}